// Round 1
// baseline (1939.713 us; speedup 1.0000x reference)
//
#include <hip/hip_runtime.h>
#include <math.h>

#define B_ 16
#define N_ 2048
#define KNN 20
#define SLOPE 0.2f
#define EPS_ 1e-5f

// ---------------------------------------------------------------- kNN
__global__ __launch_bounds__(256) void knn_kernel(const float* __restrict__ x,
                                                  int* __restrict__ idx) {
    __shared__ float xs[N_ * 3];
    int b = blockIdx.x >> 3;   // 8 blocks per batch
    int seg = blockIdx.x & 7;
    const float* xb = x + (size_t)b * N_ * 3;
    for (int i = threadIdx.x; i < N_ * 3; i += 256) xs[i] = xb[i];
    __syncthreads();

    int n = seg * 256 + threadIdx.x;
    float px = xs[n * 3], py = xs[n * 3 + 1], pz = xs[n * 3 + 2];
    float sqn = px * px + py * py + pz * pz;

    float vals[KNN];
    int inds[KNN];
#pragma unroll
    for (int j = 0; j < KNN; ++j) { vals[j] = -INFINITY; inds[j] = 0; }

    for (int m = 0; m < N_; ++m) {
        float xm = xs[m * 3], ym = xs[m * 3 + 1], zm = xs[m * 3 + 2];
        float inner = px * xm + py * ym + pz * zm;
        float sqm = xm * xm + ym * ym + zm * zm;
        float d = 2.0f * inner - sqn - sqm;
        if (d > vals[KNN - 1]) {
            float v = d; int id = m;
            bool placed = false;
#pragma unroll
            for (int j = KNN - 1; j >= 1; --j) {
                if (!placed) {
                    if (vals[j - 1] < v) { vals[j] = vals[j - 1]; inds[j] = inds[j - 1]; }
                    else { vals[j] = v; inds[j] = id; placed = true; }
                }
            }
            if (!placed) { vals[0] = v; inds[0] = id; }
        }
    }
    int* op = idx + (size_t)(b * N_ + n) * KNN;
#pragma unroll
    for (int j = 0; j < KNN; ++j) op[j] = inds[j];
}

// ------------------------------------------------------------ EdgeConv
// h[b,o,n,k] = w_edge[o,:] . [nb-ctr, ctr] + b_edge[o]
// writes pre-BN max-over-k to cat[...,0:64]; accumulates sum/sumsq over all k.
__global__ __launch_bounds__(256) void edge_kernel(const float* __restrict__ x,
                                                   const int* __restrict__ idx,
                                                   const float* __restrict__ w_edge,
                                                   const float* __restrict__ b_edge,
                                                   float* __restrict__ cat,
                                                   double* __restrict__ stats) {
    __shared__ float xs[N_ * 3];
    __shared__ float ws[64 * 6];
    __shared__ float bs[64];
    __shared__ float s_sum[64], s_sq[64];

    int b = blockIdx.x >> 5;   // 32 blocks/batch, 64 points each
    int pb = blockIdx.x & 31;
    const float* xb = x + (size_t)b * N_ * 3;
    for (int i = threadIdx.x; i < N_ * 3; i += 256) xs[i] = xb[i];
    for (int i = threadIdx.x; i < 64 * 6; i += 256) ws[i] = w_edge[i];
    if (threadIdx.x < 64) {
        bs[threadIdx.x] = b_edge[threadIdx.x];
        s_sum[threadIdx.x] = 0.f; s_sq[threadIdx.x] = 0.f;
    }
    __syncthreads();

    int p = threadIdx.x >> 2;   // point in tile
    int cg = threadIdx.x & 3;   // channel group (16 ch each)
    int n = pb * 64 + p;
    float cx = xs[n * 3], cy = xs[n * 3 + 1], cz = xs[n * 3 + 2];

    float maxv[16], sum[16], sq[16];
#pragma unroll
    for (int i = 0; i < 16; ++i) { maxv[i] = -INFINITY; sum[i] = 0.f; sq[i] = 0.f; }

    const int* ip = idx + (size_t)(b * N_ + n) * KNN;
    for (int k = 0; k < KNN; ++k) {
        int j = ip[k];
        float dx = xs[j * 3] - cx, dy = xs[j * 3 + 1] - cy, dz = xs[j * 3 + 2] - cz;
#pragma unroll
        for (int i = 0; i < 16; ++i) {
            int o = cg * 16 + i;
            const float* wr = &ws[o * 6];
            float h = bs[o] + wr[0] * dx + wr[1] * dy + wr[2] * dz
                            + wr[3] * cx + wr[4] * cy + wr[5] * cz;
            sum[i] += h; sq[i] += h * h;
            maxv[i] = fmaxf(maxv[i], h);
        }
    }

    float* cp = cat + (size_t)(b * N_ + n) * 512;
#pragma unroll
    for (int i = 0; i < 16; ++i) {
        int o = cg * 16 + i;
        cp[o] = maxv[i];
        atomicAdd(&s_sum[o], sum[i]);
        atomicAdd(&s_sq[o], sq[i]);
    }
    __syncthreads();
    if (threadIdx.x < 64) {
        atomicAdd(&stats[threadIdx.x], (double)s_sum[threadIdx.x]);
        atomicAdd(&stats[64 + threadIdx.x], (double)s_sq[threadIdx.x]);
    }
}

// --------------------------------------------------- BN + LeakyReLU (in place)
__global__ __launch_bounds__(256) void bn_kernel(float* __restrict__ cat,
                                                 const double* __restrict__ stats,
                                                 int C, int off, double invcnt) {
    int t = blockIdx.x * 256 + threadIdx.x;   // over B*N*C
    int c = t % C;
    int pn = t / C;
    double meand = stats[c] * invcnt;
    double ex2 = stats[C + c] * invcnt;
    float var = (float)(ex2 - meand * meand);
    float mean = (float)meand;
    float inv = rsqrtf(var + EPS_);
    float* p = cat + (size_t)pn * 512 + off + c;
    float v = (*p - mean) * inv;
    *p = v >= 0.f ? v : SLOPE * v;
}

// -------------------------------- graph max-pool + 1x1 conv + stats (fused)
template <int CIN, int COUT, int PPT>
__global__ __launch_bounds__(256) void layer_kernel(float* __restrict__ cat,
                                                    const int* __restrict__ idx,
                                                    const float* __restrict__ w,
                                                    const float* __restrict__ bias,
                                                    double* __restrict__ stats,
                                                    int off_in, int off_out) {
    constexpr int PG = 256 / COUT;       // point groups in conv phase
    constexpr int P = PG * PPT;          // points per block
    constexpr int PPAR = 256 / CIN;      // parallel points in gather

    __shared__ float g[P * CIN];
    __shared__ float wt[COUT * 17];
    __shared__ float s_sum[COUT], s_sq[COUT];

    int pt0 = blockIdx.x * P;            // flattened b*N+n
    int b = pt0 / N_;

    {   // gather + max over neighbors
        int c = threadIdx.x % CIN;
        int pp = threadIdx.x / CIN;
        for (int p = pp; p < P; p += PPAR) {
            const int* ip = idx + (size_t)(pt0 + p) * KNN;
            float m = -INFINITY;
#pragma unroll
            for (int k = 0; k < KNN; ++k) {
                int j = ip[k];
                m = fmaxf(m, cat[(size_t)(b * N_ + j) * 512 + off_in + c]);
            }
            g[p * CIN + c] = m;
        }
    }
    if (threadIdx.x < COUT) { s_sum[threadIdx.x] = 0.f; s_sq[threadIdx.x] = 0.f; }
    __syncthreads();

    int ot = threadIdx.x % COUT;
    int pg = threadIdx.x / COUT;
    float acc[PPT];
#pragma unroll
    for (int i = 0; i < PPT; ++i) acc[i] = 0.f;

    for (int c0 = 0; c0 < CIN; c0 += 16) {
        __syncthreads();
        for (int i = threadIdx.x; i < COUT * 16; i += 256) {
            int o = i >> 4, cc = i & 15;
            wt[o * 17 + cc] = w[(size_t)o * CIN + c0 + cc];
        }
        __syncthreads();
#pragma unroll
        for (int cc = 0; cc < 16; ++cc) {
            float wv = wt[ot * 17 + cc];
#pragma unroll
            for (int i = 0; i < PPT; ++i)
                acc[i] += wv * g[(pg + i * PG) * CIN + c0 + cc];
        }
    }

    float bo = bias[ot];
    float lsum = 0.f, lsq = 0.f;
#pragma unroll
    for (int i = 0; i < PPT; ++i) {
        float h = acc[i] + bo;
        lsum += h; lsq += h * h;
        cat[(size_t)(pt0 + pg + i * PG) * 512 + off_out + ot] = h;
    }
    atomicAdd(&s_sum[ot], lsum);
    atomicAdd(&s_sq[ot], lsq);
    __syncthreads();
    if (threadIdx.x < COUT) {
        atomicAdd(&stats[threadIdx.x], (double)s_sum[threadIdx.x]);
        atomicAdd(&stats[COUT + threadIdx.x], (double)s_sq[threadIdx.x]);
    }
}

// ------------------------- final 512->1024 GEMM + bias + max over n (partial)
__global__ __launch_bounds__(256) void final_kernel(const float* __restrict__ cat,
                                                    const float* __restrict__ w,
                                                    const float* __restrict__ bias,
                                                    float* __restrict__ partial) {
    __shared__ float As[32 * 68];   // [cc][n], 17 float4 per row
    __shared__ float Ws[32 * 68];   // [cc][o]
    __shared__ float red[16 * 64];

    int ob = blockIdx.x;    // 0..15  (o tile) — fast-varying for A reuse in L2
    int pblk = blockIdx.y;  // 0..511 (n tile)
    int pt0 = pblk * 64;
    int tx = threadIdx.x & 15;   // o dir
    int ty = threadIdx.x >> 4;   // n dir

    float acc[4][4];
#pragma unroll
    for (int i = 0; i < 4; ++i)
#pragma unroll
        for (int j = 0; j < 4; ++j) acc[i][j] = 0.f;

    for (int c0 = 0; c0 < 512; c0 += 32) {
        __syncthreads();
        int r = threadIdx.x >> 3;
        int c4 = threadIdx.x & 7;
#pragma unroll
        for (int it = 0; it < 2; ++it) {
            int row = r + it * 32;
            float4 v = *(const float4*)(cat + (size_t)(pt0 + row) * 512 + c0 + c4 * 4);
            As[(c4 * 4 + 0) * 68 + row] = v.x;
            As[(c4 * 4 + 1) * 68 + row] = v.y;
            As[(c4 * 4 + 2) * 68 + row] = v.z;
            As[(c4 * 4 + 3) * 68 + row] = v.w;
            float4 u = *(const float4*)(w + (size_t)(ob * 64 + row) * 512 + c0 + c4 * 4);
            Ws[(c4 * 4 + 0) * 68 + row] = u.x;
            Ws[(c4 * 4 + 1) * 68 + row] = u.y;
            Ws[(c4 * 4 + 2) * 68 + row] = u.z;
            Ws[(c4 * 4 + 3) * 68 + row] = u.w;
        }
        __syncthreads();
        const float4* As4 = (const float4*)As;
        const float4* Ws4 = (const float4*)Ws;
#pragma unroll
        for (int cc = 0; cc < 32; ++cc) {
            float4 a = As4[cc * 17 + ty];
            float4 wv = Ws4[cc * 17 + tx];
            float av[4] = {a.x, a.y, a.z, a.w};
            float wf[4] = {wv.x, wv.y, wv.z, wv.w};
#pragma unroll
            for (int i = 0; i < 4; ++i)
#pragma unroll
                for (int j = 0; j < 4; ++j)
                    acc[i][j] += av[i] * wf[j];
        }
    }

    float m[4];
#pragma unroll
    for (int j = 0; j < 4; ++j)
        m[j] = fmaxf(fmaxf(acc[0][j], acc[1][j]), fmaxf(acc[2][j], acc[3][j]));
    __syncthreads();
#pragma unroll
    for (int j = 0; j < 4; ++j) red[ty * 64 + tx * 4 + j] = m[j];
    __syncthreads();
    if (threadIdx.x < 64) {
        float mm = red[threadIdx.x];
#pragma unroll
        for (int rr = 1; rr < 16; ++rr) mm = fmaxf(mm, red[rr * 64 + threadIdx.x]);
        int o = ob * 64 + threadIdx.x;
        partial[(size_t)pblk * 1024 + o] = mm + bias[o];
    }
}

// ----------------------------------------------------------- final reduce
__global__ __launch_bounds__(256) void reduce_kernel(const float* __restrict__ partial,
                                                     float* __restrict__ out) {
    int t = blockIdx.x * 256 + threadIdx.x;   // 16384
    int b = t >> 10, o = t & 1023;
    float m = -INFINITY;
#pragma unroll 4
    for (int i = 0; i < 32; ++i)
        m = fmaxf(m, partial[(size_t)((b * 32 + i) * 1024) + o]);
    out[t] = m;
}

// ---------------------------------------------------------------- launch
extern "C" void kernel_launch(void* const* d_in, const int* in_sizes, int n_in,
                              void* d_out, int out_size, void* d_ws, size_t ws_size,
                              hipStream_t stream) {
    const float* x = (const float*)d_in[0];
    const float* w_edge = (const float*)d_in[1];
    const float* b_edge = (const float*)d_in[2];
    const float* w1 = (const float*)d_in[3];
    const float* b1 = (const float*)d_in[4];
    const float* w2 = (const float*)d_in[5];
    const float* b2 = (const float*)d_in[6];
    const float* w3 = (const float*)d_in[7];
    const float* b3 = (const float*)d_in[8];
    const float* w_final = (const float*)d_in[9];
    const float* b_final = (const float*)d_in[10];
    float* out = (float*)d_out;

    char* ws = (char*)d_ws;
    int* idx = (int*)ws;                                    // B*N*K ints = 2.62 MB
    float* cat = (float*)(ws + 2621440);                    // B*N*512 f32 = 67.1 MB
    float* partial = (float*)(ws + 69730304);               // 512*1024 f32 = 2 MB
    double* stats = (double*)(ws + 71827456);               // 1024 doubles
    double* st_e = stats;          // 64ch  -> [0,128)
    double* st_1 = stats + 128;    // 64ch  -> [128,256)
    double* st_2 = stats + 256;    // 128ch -> [256,512)
    double* st_3 = stats + 512;    // 256ch -> [512,1024)

    hipMemsetAsync(stats, 0, 1024 * sizeof(double), stream);

    knn_kernel<<<B_ * 8, 256, 0, stream>>>(x, idx);
    edge_kernel<<<B_ * 32, 256, 0, stream>>>(x, idx, w_edge, b_edge, cat, st_e);
    bn_kernel<<<(B_ * N_ * 64) / 256, 256, 0, stream>>>(cat, st_e, 64, 0,
                                                        1.0 / ((double)B_ * N_ * KNN));
    layer_kernel<64, 64, 16><<<(B_ * N_) / 64, 256, 0, stream>>>(cat, idx, w1, b1, st_1, 0, 64);
    bn_kernel<<<(B_ * N_ * 64) / 256, 256, 0, stream>>>(cat, st_1, 64, 64,
                                                        1.0 / ((double)B_ * N_));
    layer_kernel<64, 128, 16><<<(B_ * N_) / 32, 256, 0, stream>>>(cat, idx, w2, b2, st_2, 64, 128);
    bn_kernel<<<(B_ * N_ * 128) / 256, 256, 0, stream>>>(cat, st_2, 128, 128,
                                                         1.0 / ((double)B_ * N_));
    layer_kernel<128, 256, 16><<<(B_ * N_) / 16, 256, 0, stream>>>(cat, idx, w3, b3, st_3, 128, 256);
    bn_kernel<<<(B_ * N_ * 256) / 256, 256, 0, stream>>>(cat, st_3, 256, 256,
                                                         1.0 / ((double)B_ * N_));
    final_kernel<<<dim3(16, 512), 256, 0, stream>>>(cat, w_final, b_final, partial);
    reduce_kernel<<<64, 256, 0, stream>>>(partial, out);
}

// Round 2
// 1051.475 us; speedup vs baseline: 1.8448x; 1.8448x over previous
//
#include <hip/hip_runtime.h>
#include <math.h>

#define B_ 16
#define N_ 2048
#define KNN 20
#define SLOPE 0.2f
#define EPS_ 1e-5f

#define SEG 8
#define SEGLEN (N_ / SEG)   // 256
#define QPB 32              // queries per block

// ---------------------------------------------------------------- kNN
// Block = 256 threads = 8 segments x 32 queries. Each thread keeps a
// register-resident sorted top-20 of its 256-candidate segment (branch-free
// carried insert), lists merge 8-way through LDS. Points LDS is union-ed
// with the merge lists (disjoint lifetimes) to stay at ~43 KB -> 3 blocks/CU.
__global__ __launch_bounds__(256, 2) void knn_kernel(const float* __restrict__ x,
                                                     int* __restrict__ idx) {
    constexpr int QS = SEG * KNN + 1;   // 161: odd stride breaks bank aliasing
    __shared__ union U {
        float pts[4 * N_];                                   // x,y,z,|p|^2 SoA
        struct { float sv[QPB * QS]; int si[QPB * QS]; } l;  // merge lists
    } u;
    __shared__ int shp[QPB * SEG];

    const int b = blockIdx.x >> 6;    // 64 blocks per batch
    const int qb = blockIdx.x & 63;
    const float* xb = x + (size_t)b * N_ * 3;
    for (int i = threadIdx.x; i < N_; i += 256) {
        float xv = xb[i * 3], yv = xb[i * 3 + 1], zv = xb[i * 3 + 2];
        u.pts[i] = xv; u.pts[N_ + i] = yv; u.pts[2 * N_ + i] = zv;
        u.pts[3 * N_ + i] = xv * xv + yv * yv + zv * zv;
    }
    shp[threadIdx.x] = 0;
    __syncthreads();

    const int s = threadIdx.x >> 5;   // segment (uniform per half-wave)
    const int q = threadIdx.x & 31;   // query within block
    const int n = qb * QPB + q;
    const float px = u.pts[n], py = u.pts[N_ + n], pz = u.pts[2 * N_ + n];
    const float sqn = u.pts[3 * N_ + n];

    float vals[KNN]; int inds[KNN];
#pragma unroll
    for (int j = 0; j < KNN; ++j) { vals[j] = -INFINITY; inds[j] = 0; }

    const int m0 = s * SEGLEN;
    for (int i = 0; i < SEGLEN; ++i) {
        const int m = m0 + i;
        const float xm = u.pts[m], ym = u.pts[N_ + m], zm = u.pts[2 * N_ + m];
        const float d = 2.0f * (px * xm + py * ym + pz * zm) - sqn - u.pts[3 * N_ + m];
        if (d > vals[KNN - 1]) {
            // carried insert: bubble (cv,ci) down the sorted list, branch-free
            float cv = d; int ci = m;
#pragma unroll
            for (int j = 0; j < KNN; ++j) {
                const bool sw = cv > vals[j];
                const float tv = vals[j]; const int ti = inds[j];
                vals[j] = sw ? cv : tv;  inds[j] = sw ? ci : ti;
                cv      = sw ? tv : cv;  ci      = sw ? ti : ci;
            }
        }
    }
    __syncthreads();   // everyone done reading u.pts before lists overwrite it
    {
        float* sv = u.l.sv + q * QS + s * KNN;
        int*   si = u.l.si + q * QS + s * KNN;
#pragma unroll
        for (int j = 0; j < KNN; ++j) { sv[j] = vals[j]; si[j] = inds[j]; }
    }
    __syncthreads();
    if (threadIdx.x < QPB) {           // one merger thread per query
        const int qq = threadIdx.x;
        int* op = idx + (size_t)(b * N_ + qb * QPB + qq) * KNN;
        const float* sv = u.l.sv + qq * QS;
        const int*   si = u.l.si + qq * QS;
        int* hp = shp + qq * SEG;
        for (int j = 0; j < KNN; ++j) {
            float best = -INFINITY; int bs = 0;
#pragma unroll
            for (int s2 = 0; s2 < SEG; ++s2) {
                const float v = sv[s2 * KNN + hp[s2]];
                if (v > best) { best = v; bs = s2; }   // strict >, s ascending: ties -> smaller index
            }
            const int h = hp[bs];
            op[j] = si[bs * KNN + h];
            hp[bs] = h + 1;
        }
    }
}

// ------------------------------------------------------------ EdgeConv
__global__ __launch_bounds__(256) void edge_kernel(const float* __restrict__ x,
                                                   const int* __restrict__ idx,
                                                   const float* __restrict__ w_edge,
                                                   const float* __restrict__ b_edge,
                                                   float* __restrict__ cat,
                                                   double* __restrict__ stats) {
    __shared__ float xs[N_ * 3];
    __shared__ float ws[64 * 6];
    __shared__ float bs[64];
    __shared__ float s_sum[64], s_sq[64];

    int b = blockIdx.x >> 5;
    int pb = blockIdx.x & 31;
    const float* xb = x + (size_t)b * N_ * 3;
    for (int i = threadIdx.x; i < N_ * 3; i += 256) xs[i] = xb[i];
    for (int i = threadIdx.x; i < 64 * 6; i += 256) ws[i] = w_edge[i];
    if (threadIdx.x < 64) {
        bs[threadIdx.x] = b_edge[threadIdx.x];
        s_sum[threadIdx.x] = 0.f; s_sq[threadIdx.x] = 0.f;
    }
    __syncthreads();

    int p = threadIdx.x >> 2;
    int cg = threadIdx.x & 3;
    int n = pb * 64 + p;
    float cx = xs[n * 3], cy = xs[n * 3 + 1], cz = xs[n * 3 + 2];

    float maxv[16], sum[16], sq[16];
#pragma unroll
    for (int i = 0; i < 16; ++i) { maxv[i] = -INFINITY; sum[i] = 0.f; sq[i] = 0.f; }

    const int* ip = idx + (size_t)(b * N_ + n) * KNN;
    for (int k = 0; k < KNN; ++k) {
        int j = ip[k];
        float dx = xs[j * 3] - cx, dy = xs[j * 3 + 1] - cy, dz = xs[j * 3 + 2] - cz;
#pragma unroll
        for (int i = 0; i < 16; ++i) {
            int o = cg * 16 + i;
            const float* wr = &ws[o * 6];
            float h = bs[o] + wr[0] * dx + wr[1] * dy + wr[2] * dz
                            + wr[3] * cx + wr[4] * cy + wr[5] * cz;
            sum[i] += h; sq[i] += h * h;
            maxv[i] = fmaxf(maxv[i], h);
        }
    }

    float* cp = cat + (size_t)(b * N_ + n) * 512;
#pragma unroll
    for (int i = 0; i < 16; ++i) {
        int o = cg * 16 + i;
        cp[o] = maxv[i];
        atomicAdd(&s_sum[o], sum[i]);
        atomicAdd(&s_sq[o], sq[i]);
    }
    __syncthreads();
    if (threadIdx.x < 64) {
        atomicAdd(&stats[threadIdx.x], (double)s_sum[threadIdx.x]);
        atomicAdd(&stats[64 + threadIdx.x], (double)s_sq[threadIdx.x]);
    }
}

// --------------------------------------------------- BN + LeakyReLU (in place)
__global__ __launch_bounds__(256) void bn_kernel(float* __restrict__ cat,
                                                 const double* __restrict__ stats,
                                                 int C, int off, double invcnt) {
    int t = blockIdx.x * 256 + threadIdx.x;
    int c = t % C;
    int pn = t / C;
    double meand = stats[c] * invcnt;
    double ex2 = stats[C + c] * invcnt;
    float var = (float)(ex2 - meand * meand);
    float mean = (float)meand;
    float inv = rsqrtf(var + EPS_);
    float* p = cat + (size_t)pn * 512 + off + c;
    float v = (*p - mean) * inv;
    *p = v >= 0.f ? v : SLOPE * v;
}

// -------------------------------- graph max-pool + 1x1 conv + stats (fused)
template <int CIN, int COUT, int PPT>
__global__ __launch_bounds__(256) void layer_kernel(float* __restrict__ cat,
                                                    const int* __restrict__ idx,
                                                    const float* __restrict__ w,
                                                    const float* __restrict__ bias,
                                                    double* __restrict__ stats,
                                                    int off_in, int off_out) {
    constexpr int PG = 256 / COUT;
    constexpr int P = PG * PPT;
    constexpr int PPAR = 256 / CIN;

    __shared__ float g[P * CIN];
    __shared__ float wt[COUT * 17];
    __shared__ float s_sum[COUT], s_sq[COUT];

    int pt0 = blockIdx.x * P;
    int b = pt0 / N_;

    {
        int c = threadIdx.x % CIN;
        int pp = threadIdx.x / CIN;
        for (int p = pp; p < P; p += PPAR) {
            const int* ip = idx + (size_t)(pt0 + p) * KNN;
            float m = -INFINITY;
#pragma unroll
            for (int k = 0; k < KNN; ++k) {
                int j = ip[k];
                m = fmaxf(m, cat[(size_t)(b * N_ + j) * 512 + off_in + c]);
            }
            g[p * CIN + c] = m;
        }
    }
    if (threadIdx.x < COUT) { s_sum[threadIdx.x] = 0.f; s_sq[threadIdx.x] = 0.f; }
    __syncthreads();

    int ot = threadIdx.x % COUT;
    int pg = threadIdx.x / COUT;
    float acc[PPT];
#pragma unroll
    for (int i = 0; i < PPT; ++i) acc[i] = 0.f;

    for (int c0 = 0; c0 < CIN; c0 += 16) {
        __syncthreads();
        for (int i = threadIdx.x; i < COUT * 16; i += 256) {
            int o = i >> 4, cc = i & 15;
            wt[o * 17 + cc] = w[(size_t)o * CIN + c0 + cc];
        }
        __syncthreads();
#pragma unroll
        for (int cc = 0; cc < 16; ++cc) {
            float wv = wt[ot * 17 + cc];
#pragma unroll
            for (int i = 0; i < PPT; ++i)
                acc[i] += wv * g[(pg + i * PG) * CIN + c0 + cc];
        }
    }

    float bo = bias[ot];
    float lsum = 0.f, lsq = 0.f;
#pragma unroll
    for (int i = 0; i < PPT; ++i) {
        float h = acc[i] + bo;
        lsum += h; lsq += h * h;
        cat[(size_t)(pt0 + pg + i * PG) * 512 + off_out + ot] = h;
    }
    atomicAdd(&s_sum[ot], lsum);
    atomicAdd(&s_sq[ot], lsq);
    __syncthreads();
    if (threadIdx.x < COUT) {
        atomicAdd(&stats[threadIdx.x], (double)s_sum[threadIdx.x]);
        atomicAdd(&stats[COUT + threadIdx.x], (double)s_sq[threadIdx.x]);
    }
}

// ------------------------- final 512->1024 GEMM + bias + max over n (partial)
// 128x128 tile, 8x8 acc/thread: 64 FMA per 4 ds_read_b128 -> FMA-issue bound.
__global__ __launch_bounds__(256) void final_kernel(const float* __restrict__ cat,
                                                    const float* __restrict__ w,
                                                    const float* __restrict__ bias,
                                                    float* __restrict__ partial) {
    __shared__ float As[16 * 132];   // [c][n], pad 128->132
    __shared__ float Ws[16 * 132];   // [c][o]
    __shared__ float red[16 * 128];

    const int ob = blockIdx.x;    // 0..7   (o tile), fast-varying: A tile L2-hot
    const int pblk = blockIdx.y;  // 0..255 (n tile)
    const int pt0 = pblk * 128;
    const int tx = threadIdx.x & 15;
    const int ty = threadIdx.x >> 4;

    float acc[8][8];
#pragma unroll
    for (int i = 0; i < 8; ++i)
#pragma unroll
        for (int j = 0; j < 8; ++j) acc[i][j] = 0.f;

    const int row = threadIdx.x & 127;
    const int half = threadIdx.x >> 7;
    const float* arow = cat + (size_t)(pt0 + row) * 512 + half * 8;
    const float* wrow = w + (size_t)(ob * 128 + row) * 512 + half * 8;

    for (int c0 = 0; c0 < 512; c0 += 16) {
        __syncthreads();
        float4 v0 = *(const float4*)(arow + c0);
        float4 v1 = *(const float4*)(arow + c0 + 4);
        float4 u0 = *(const float4*)(wrow + c0);
        float4 u1 = *(const float4*)(wrow + c0 + 4);
        const int cb = half * 8;
        As[(cb + 0) * 132 + row] = v0.x; As[(cb + 1) * 132 + row] = v0.y;
        As[(cb + 2) * 132 + row] = v0.z; As[(cb + 3) * 132 + row] = v0.w;
        As[(cb + 4) * 132 + row] = v1.x; As[(cb + 5) * 132 + row] = v1.y;
        As[(cb + 6) * 132 + row] = v1.z; As[(cb + 7) * 132 + row] = v1.w;
        Ws[(cb + 0) * 132 + row] = u0.x; Ws[(cb + 1) * 132 + row] = u0.y;
        Ws[(cb + 2) * 132 + row] = u0.z; Ws[(cb + 3) * 132 + row] = u0.w;
        Ws[(cb + 4) * 132 + row] = u1.x; Ws[(cb + 5) * 132 + row] = u1.y;
        Ws[(cb + 6) * 132 + row] = u1.z; Ws[(cb + 7) * 132 + row] = u1.w;
        __syncthreads();
#pragma unroll
        for (int cc = 0; cc < 16; ++cc) {
            const float4* Ap = (const float4*)(As + cc * 132);
            const float4* Wp = (const float4*)(Ws + cc * 132);
            float4 a0 = Ap[ty], a1 = Ap[ty + 16];
            float4 w0 = Wp[tx], w1 = Wp[tx + 16];
            float av[8] = {a0.x, a0.y, a0.z, a0.w, a1.x, a1.y, a1.z, a1.w};
            float wv[8] = {w0.x, w0.y, w0.z, w0.w, w1.x, w1.y, w1.z, w1.w};
#pragma unroll
            for (int i = 0; i < 8; ++i)
#pragma unroll
                for (int j = 0; j < 8; ++j)
                    acc[i][j] += av[i] * wv[j];
        }
    }

#pragma unroll
    for (int j = 0; j < 8; ++j) {
        float mm = acc[0][j];
#pragma unroll
        for (int i = 1; i < 8; ++i) mm = fmaxf(mm, acc[i][j]);
        const int o = (j < 4) ? tx * 4 + j : 64 + tx * 4 + (j - 4);
        red[ty * 128 + o] = mm;
    }
    __syncthreads();
    if (threadIdx.x < 128) {
        const int o = threadIdx.x;
        float mm = red[o];
#pragma unroll
        for (int r = 1; r < 16; ++r) mm = fmaxf(mm, red[r * 128 + o]);
        partial[(size_t)pblk * 1024 + ob * 128 + o] = mm + bias[ob * 128 + o];
    }
}

// ----------------------------------------------------------- final reduce
__global__ __launch_bounds__(256) void reduce_kernel(const float* __restrict__ partial,
                                                     float* __restrict__ out) {
    int t = blockIdx.x * 256 + threadIdx.x;   // 16384
    int b = t >> 10, o = t & 1023;
    float m = -INFINITY;
#pragma unroll 4
    for (int i = 0; i < 16; ++i)
        m = fmaxf(m, partial[(size_t)((b * 16 + i) * 1024) + o]);
    out[t] = m;
}

// ---------------------------------------------------------------- launch
extern "C" void kernel_launch(void* const* d_in, const int* in_sizes, int n_in,
                              void* d_out, int out_size, void* d_ws, size_t ws_size,
                              hipStream_t stream) {
    const float* x = (const float*)d_in[0];
    const float* w_edge = (const float*)d_in[1];
    const float* b_edge = (const float*)d_in[2];
    const float* w1 = (const float*)d_in[3];
    const float* b1 = (const float*)d_in[4];
    const float* w2 = (const float*)d_in[5];
    const float* b2 = (const float*)d_in[6];
    const float* w3 = (const float*)d_in[7];
    const float* b3 = (const float*)d_in[8];
    const float* w_final = (const float*)d_in[9];
    const float* b_final = (const float*)d_in[10];
    float* out = (float*)d_out;

    char* ws = (char*)d_ws;
    int* idx = (int*)ws;                                    // 2.62 MB
    float* cat = (float*)(ws + 2621440);                    // 67.1 MB
    float* partial = (float*)(ws + 69730304);               // 1 MB (256x1024)
    double* stats = (double*)(ws + 71827456);               // 1024 doubles
    double* st_e = stats;
    double* st_1 = stats + 128;
    double* st_2 = stats + 256;
    double* st_3 = stats + 512;

    hipMemsetAsync(stats, 0, 1024 * sizeof(double), stream);

    knn_kernel<<<B_ * 64, 256, 0, stream>>>(x, idx);
    edge_kernel<<<B_ * 32, 256, 0, stream>>>(x, idx, w_edge, b_edge, cat, st_e);
    bn_kernel<<<(B_ * N_ * 64) / 256, 256, 0, stream>>>(cat, st_e, 64, 0,
                                                        1.0 / ((double)B_ * N_ * KNN));
    layer_kernel<64, 64, 16><<<(B_ * N_) / 64, 256, 0, stream>>>(cat, idx, w1, b1, st_1, 0, 64);
    bn_kernel<<<(B_ * N_ * 64) / 256, 256, 0, stream>>>(cat, st_1, 64, 64,
                                                        1.0 / ((double)B_ * N_));
    layer_kernel<64, 128, 16><<<(B_ * N_) / 32, 256, 0, stream>>>(cat, idx, w2, b2, st_2, 64, 128);
    bn_kernel<<<(B_ * N_ * 128) / 256, 256, 0, stream>>>(cat, st_2, 128, 128,
                                                         1.0 / ((double)B_ * N_));
    layer_kernel<128, 256, 16><<<(B_ * N_) / 16, 256, 0, stream>>>(cat, idx, w3, b3, st_3, 128, 256);
    bn_kernel<<<(B_ * N_ * 256) / 256, 256, 0, stream>>>(cat, st_3, 256, 256,
                                                         1.0 / ((double)B_ * N_));
    final_kernel<<<dim3(8, 256), 256, 0, stream>>>(cat, w_final, b_final, partial);
    reduce_kernel<<<64, 256, 0, stream>>>(partial, out);
}

// Round 4
// 731.149 us; speedup vs baseline: 2.6530x; 1.4381x over previous
//
#include <hip/hip_runtime.h>
#include <hip/hip_bf16.h>
#include <math.h>

#define B_ 16
#define N_ 2048
#define KNN 20
#define SLOPE 0.2f
#define EPS_ 1e-5f

#define SEG 8
#define SEGLEN (N_ / SEG)   // 256
#define QPB 32              // queries per block

typedef __attribute__((ext_vector_type(8))) short short8;
typedef __attribute__((ext_vector_type(4))) float float4v;

// ---------------------------------------------------------------- kNN
__global__ __launch_bounds__(256, 2) void knn_kernel(const float* __restrict__ x,
                                                     int* __restrict__ idx) {
    constexpr int QS = SEG * KNN + 1;   // 161: odd stride breaks bank aliasing
    __shared__ union U {
        float pts[4 * N_];                                   // x,y,z,|p|^2 SoA
        struct { float sv[QPB * QS]; int si[QPB * QS]; } l;  // merge lists
    } u;
    __shared__ int shp[QPB * SEG];

    const int b = blockIdx.x >> 6;    // 64 blocks per batch
    const int qb = blockIdx.x & 63;
    const float* xb = x + (size_t)b * N_ * 3;
    for (int i = threadIdx.x; i < N_; i += 256) {
        float xv = xb[i * 3], yv = xb[i * 3 + 1], zv = xb[i * 3 + 2];
        u.pts[i] = xv; u.pts[N_ + i] = yv; u.pts[2 * N_ + i] = zv;
        u.pts[3 * N_ + i] = xv * xv + yv * yv + zv * zv;
    }
    shp[threadIdx.x] = 0;
    __syncthreads();

    const int s = threadIdx.x >> 5;
    const int q = threadIdx.x & 31;
    const int n = qb * QPB + q;
    const float px = u.pts[n], py = u.pts[N_ + n], pz = u.pts[2 * N_ + n];
    const float sqn = u.pts[3 * N_ + n];

    float vals[KNN]; int inds[KNN];
#pragma unroll
    for (int j = 0; j < KNN; ++j) { vals[j] = -INFINITY; inds[j] = 0; }

    const int m0 = s * SEGLEN;
    for (int i = 0; i < SEGLEN; ++i) {
        const int m = m0 + i;
        const float xm = u.pts[m], ym = u.pts[N_ + m], zm = u.pts[2 * N_ + m];
        const float d = 2.0f * (px * xm + py * ym + pz * zm) - sqn - u.pts[3 * N_ + m];
        if (d > vals[KNN - 1]) {
            float cv = d; int ci = m;
#pragma unroll
            for (int j = 0; j < KNN; ++j) {
                const bool sw = cv > vals[j];
                const float tv = vals[j]; const int ti = inds[j];
                vals[j] = sw ? cv : tv;  inds[j] = sw ? ci : ti;
                cv      = sw ? tv : cv;  ci      = sw ? ti : ci;
            }
        }
    }
    __syncthreads();
    {
        float* sv = u.l.sv + q * QS + s * KNN;
        int*   si = u.l.si + q * QS + s * KNN;
#pragma unroll
        for (int j = 0; j < KNN; ++j) { sv[j] = vals[j]; si[j] = inds[j]; }
    }
    __syncthreads();
    if (threadIdx.x < QPB) {
        const int qq = threadIdx.x;
        int* op = idx + (size_t)(b * N_ + qb * QPB + qq) * KNN;
        const float* sv = u.l.sv + qq * QS;
        const int*   si = u.l.si + qq * QS;
        int* hp = shp + qq * SEG;
        for (int j = 0; j < KNN; ++j) {
            float best = -INFINITY; int bs = 0;
#pragma unroll
            for (int s2 = 0; s2 < SEG; ++s2) {
                const float v = sv[s2 * KNN + hp[s2]];
                if (v > best) { best = v; bs = s2; }
            }
            const int h = hp[bs];
            op[j] = si[bs * KNN + h];
            hp[bs] = h + 1;
        }
    }
}

// ------------------------------------------------------------ EdgeConv
__global__ __launch_bounds__(256) void edge_kernel(const float* __restrict__ x,
                                                   const int* __restrict__ idx,
                                                   const float* __restrict__ w_edge,
                                                   const float* __restrict__ b_edge,
                                                   float* __restrict__ cat,
                                                   double* __restrict__ stats) {
    __shared__ float xs[N_ * 3];
    __shared__ float ws[64 * 6];
    __shared__ float bs[64];
    __shared__ float s_sum[64], s_sq[64];

    int b = blockIdx.x >> 5;
    int pb = blockIdx.x & 31;
    const float* xb = x + (size_t)b * N_ * 3;
    for (int i = threadIdx.x; i < N_ * 3; i += 256) xs[i] = xb[i];
    for (int i = threadIdx.x; i < 64 * 6; i += 256) ws[i] = w_edge[i];
    if (threadIdx.x < 64) {
        bs[threadIdx.x] = b_edge[threadIdx.x];
        s_sum[threadIdx.x] = 0.f; s_sq[threadIdx.x] = 0.f;
    }
    __syncthreads();

    int p = threadIdx.x >> 2;
    int cg = threadIdx.x & 3;
    int n = pb * 64 + p;
    float cx = xs[n * 3], cy = xs[n * 3 + 1], cz = xs[n * 3 + 2];

    float maxv[16], sum[16], sq[16];
#pragma unroll
    for (int i = 0; i < 16; ++i) { maxv[i] = -INFINITY; sum[i] = 0.f; sq[i] = 0.f; }

    const int* ip = idx + (size_t)(b * N_ + n) * KNN;
    for (int k = 0; k < KNN; ++k) {
        int j = ip[k];
        float dx = xs[j * 3] - cx, dy = xs[j * 3 + 1] - cy, dz = xs[j * 3 + 2] - cz;
#pragma unroll
        for (int i = 0; i < 16; ++i) {
            int o = cg * 16 + i;
            const float* wr = &ws[o * 6];
            float h = bs[o] + wr[0] * dx + wr[1] * dy + wr[2] * dz
                            + wr[3] * cx + wr[4] * cy + wr[5] * cz;
            sum[i] += h; sq[i] += h * h;
            maxv[i] = fmaxf(maxv[i], h);
        }
    }

    float* cp = cat + (size_t)(b * N_ + n) * 512;
#pragma unroll
    for (int i = 0; i < 16; ++i) {
        int o = cg * 16 + i;
        cp[o] = maxv[i];
        atomicAdd(&s_sum[o], sum[i]);
        atomicAdd(&s_sq[o], sq[i]);
    }
    __syncthreads();
    if (threadIdx.x < 64) {
        atomicAdd(&stats[threadIdx.x], (double)s_sum[threadIdx.x]);
        atomicAdd(&stats[64 + threadIdx.x], (double)s_sq[threadIdx.x]);
    }
}

// ------------------------- BN + LeakyReLU (in place) + bf16 mirror copy
__global__ __launch_bounds__(256) void bn_kernel(float* __restrict__ cat,
                                                 __hip_bfloat16* __restrict__ catb,
                                                 const double* __restrict__ stats,
                                                 int C, int off, double invcnt) {
    int t = blockIdx.x * 256 + threadIdx.x;
    int c = t % C;
    int pn = t / C;
    double meand = stats[c] * invcnt;
    double ex2 = stats[C + c] * invcnt;
    float var = (float)(ex2 - meand * meand);
    float mean = (float)meand;
    float inv = rsqrtf(var + EPS_);
    size_t o = (size_t)pn * 512 + off + c;
    float v = (cat[o] - mean) * inv;
    v = v >= 0.f ? v : SLOPE * v;
    cat[o] = v;
    if (catb) catb[o] = __float2bfloat16(v);
}

// ----------------------------------------------------- w_final -> bf16
__global__ __launch_bounds__(256) void wconv_kernel(const float* __restrict__ w,
                                                    __hip_bfloat16* __restrict__ wb) {
    int t = blockIdx.x * 256 + threadIdx.x;   // 1024*512
    wb[t] = __float2bfloat16(w[t]);
}

// -------------------------------- graph max-pool + 1x1 conv + stats (fused)
template <int CIN, int COUT, int PPT>
__global__ __launch_bounds__(256) void layer_kernel(float* __restrict__ cat,
                                                    const int* __restrict__ idx,
                                                    const float* __restrict__ w,
                                                    const float* __restrict__ bias,
                                                    double* __restrict__ stats,
                                                    int off_in, int off_out) {
    constexpr int PG = 256 / COUT;
    constexpr int P = PG * PPT;
    constexpr int PPAR = 256 / CIN;

    __shared__ float g[P * CIN];
    __shared__ float wt[COUT * 17];
    __shared__ float s_sum[COUT], s_sq[COUT];

    int pt0 = blockIdx.x * P;
    int b = pt0 / N_;

    {
        int c = threadIdx.x % CIN;
        int pp = threadIdx.x / CIN;
        for (int p = pp; p < P; p += PPAR) {
            const int* ip = idx + (size_t)(pt0 + p) * KNN;
            float m = -INFINITY;
#pragma unroll
            for (int k = 0; k < KNN; ++k) {
                int j = ip[k];
                m = fmaxf(m, cat[(size_t)(b * N_ + j) * 512 + off_in + c]);
            }
            g[p * CIN + c] = m;
        }
    }
    if (threadIdx.x < COUT) { s_sum[threadIdx.x] = 0.f; s_sq[threadIdx.x] = 0.f; }
    __syncthreads();

    int ot = threadIdx.x % COUT;
    int pg = threadIdx.x / COUT;
    float acc[PPT];
#pragma unroll
    for (int i = 0; i < PPT; ++i) acc[i] = 0.f;

    for (int c0 = 0; c0 < CIN; c0 += 16) {
        __syncthreads();
        for (int i = threadIdx.x; i < COUT * 16; i += 256) {
            int o = i >> 4, cc = i & 15;
            wt[o * 17 + cc] = w[(size_t)o * CIN + c0 + cc];
        }
        __syncthreads();
#pragma unroll
        for (int cc = 0; cc < 16; ++cc) {
            float wv = wt[ot * 17 + cc];
#pragma unroll
            for (int i = 0; i < PPT; ++i)
                acc[i] += wv * g[(pg + i * PG) * CIN + c0 + cc];
        }
    }

    float bo = bias[ot];
    float lsum = 0.f, lsq = 0.f;
#pragma unroll
    for (int i = 0; i < PPT; ++i) {
        float h = acc[i] + bo;
        lsum += h; lsq += h * h;
        cat[(size_t)(pt0 + pg + i * PG) * 512 + off_out + ot] = h;
    }
    atomicAdd(&s_sum[ot], lsum);
    atomicAdd(&s_sq[ot], lsq);
    __syncthreads();
    if (threadIdx.x < COUT) {
        atomicAdd(&stats[threadIdx.x], (double)s_sum[threadIdx.x]);
        atomicAdd(&stats[COUT + threadIdx.x], (double)s_sq[threadIdx.x]);
    }
}

// -------------- final GEMM via bf16 MFMA + bias + max-over-n (register staging)
// A = catb [32768][512], B = wb [1024][512] (B^T form). 128x128 tile, BK=64,
// 2x2 wave grid, 4x4 16x16x32 fragments/wave, one-step global prefetch.
__global__ __launch_bounds__(256) void final_mfma_kernel(const short* __restrict__ catb,
                                                         const short* __restrict__ wb,
                                                         const float* __restrict__ bias,
                                                         float* __restrict__ partial) {
    constexpr int LDK = 72;              // 64 + 8 pad: 144 B row stride (16B-aligned)
    __shared__ short As[128 * LDK];
    __shared__ short Bs[128 * LDK];
    __shared__ float red[256];

    const int ob = blockIdx.x;     // 0..7, fast-varying: A tile stays L2/LLC-hot
    const int pblk = blockIdx.y;   // 0..255
    const int pt0 = pblk * 128;

    const int wid = threadIdx.x >> 6;
    const int lane = threadIdx.x & 63;
    const int wm = wid >> 1, wn = wid & 1;   // 2x2 wave grid -> 64x64 per wave
    const int lm = lane & 15, g = lane >> 4;

    // staging map: 2 threads per tile row, 32 cols (4 x short8) each
    const int srow = threadIdx.x >> 1;
    const int scg = (threadIdx.x & 1) * 32;
    const short* ga = catb + (size_t)(pt0 + srow) * 512 + scg;
    const short* gb = wb + (size_t)(ob * 128 + srow) * 512 + scg;
    short* la = As + srow * LDK + scg;
    short* lb = Bs + srow * LDK + scg;

    float4v acc[4][4];
#pragma unroll
    for (int i = 0; i < 4; ++i)
#pragma unroll
        for (int j = 0; j < 4; ++j) acc[i][j] = {0.f, 0.f, 0.f, 0.f};

    short8 ra[4], rb[4];
#pragma unroll
    for (int j = 0; j < 4; ++j) {
        ra[j] = *(const short8*)(ga + j * 8);
        rb[j] = *(const short8*)(gb + j * 8);
    }

    for (int step = 0; step < 8; ++step) {
        __syncthreads();               // previous iteration's LDS reads done
#pragma unroll
        for (int j = 0; j < 4; ++j) {
            *(short8*)(la + j * 8) = ra[j];
            *(short8*)(lb + j * 8) = rb[j];
        }
        __syncthreads();
        if (step < 7) {                // prefetch next slab under the MFMAs
            const int c1 = (step + 1) * 64;
#pragma unroll
            for (int j = 0; j < 4; ++j) {
                ra[j] = *(const short8*)(ga + c1 + j * 8);
                rb[j] = *(const short8*)(gb + c1 + j * 8);
            }
        }
#pragma unroll
        for (int kk = 0; kk < 2; ++kk) {
            short8 a[4], b[4];
#pragma unroll
            for (int t = 0; t < 4; ++t) {
                a[t] = *(const short8*)&As[(wm * 64 + t * 16 + lm) * LDK + kk * 32 + g * 8];
                b[t] = *(const short8*)&Bs[(wn * 64 + t * 16 + lm) * LDK + kk * 32 + g * 8];
            }
#pragma unroll
            for (int mt = 0; mt < 4; ++mt)
#pragma unroll
                for (int nt = 0; nt < 4; ++nt)
                    acc[mt][nt] = __builtin_amdgcn_mfma_f32_16x16x32_bf16(
                        a[mt], b[nt], acc[mt][nt], 0, 0, 0);
        }
    }

    // epilogue: max over this wave's 64 m-rows per output column n
    float cm[4];
#pragma unroll
    for (int nt = 0; nt < 4; ++nt) {
        float m = -INFINITY;
#pragma unroll
        for (int mt = 0; mt < 4; ++mt)
#pragma unroll
            for (int r = 0; r < 4; ++r) m = fmaxf(m, acc[mt][nt][r]);
        m = fmaxf(m, __shfl_xor(m, 16, 64));
        m = fmaxf(m, __shfl_xor(m, 32, 64));
        cm[nt] = m;
    }
    __syncthreads();                   // As/Bs no longer needed; red is separate
    if (lane < 16) {
#pragma unroll
        for (int nt = 0; nt < 4; ++nt)
            red[wm * 128 + wn * 64 + nt * 16 + lane] = cm[nt];
    }
    __syncthreads();
    if (threadIdx.x < 128) {
        const int o = threadIdx.x;
        float v = fmaxf(red[o], red[128 + o]) + bias[ob * 128 + o];
        partial[(size_t)pblk * 1024 + ob * 128 + o] = v;
    }
}

// ---------------------- fp32 fallback final GEMM (if workspace too small)
__global__ __launch_bounds__(256) void final_kernel(const float* __restrict__ cat,
                                                    const float* __restrict__ w,
                                                    const float* __restrict__ bias,
                                                    float* __restrict__ partial) {
    __shared__ float As[16 * 132];
    __shared__ float Ws[16 * 132];
    __shared__ float red[16 * 128];

    const int ob = blockIdx.x;
    const int pblk = blockIdx.y;
    const int pt0 = pblk * 128;
    const int tx = threadIdx.x & 15;
    const int ty = threadIdx.x >> 4;

    float acc[8][8];
#pragma unroll
    for (int i = 0; i < 8; ++i)
#pragma unroll
        for (int j = 0; j < 8; ++j) acc[i][j] = 0.f;

    const int row = threadIdx.x & 127;
    const int half = threadIdx.x >> 7;
    const float* arow = cat + (size_t)(pt0 + row) * 512 + half * 8;
    const float* wrow = w + (size_t)(ob * 128 + row) * 512 + half * 8;

    for (int c0 = 0; c0 < 512; c0 += 16) {
        __syncthreads();
        float4 v0 = *(const float4*)(arow + c0);
        float4 v1 = *(const float4*)(arow + c0 + 4);
        float4 u0 = *(const float4*)(wrow + c0);
        float4 u1 = *(const float4*)(wrow + c0 + 4);
        const int cb = half * 8;
        As[(cb + 0) * 132 + row] = v0.x; As[(cb + 1) * 132 + row] = v0.y;
        As[(cb + 2) * 132 + row] = v0.z; As[(cb + 3) * 132 + row] = v0.w;
        As[(cb + 4) * 132 + row] = v1.x; As[(cb + 5) * 132 + row] = v1.y;
        As[(cb + 6) * 132 + row] = v1.z; As[(cb + 7) * 132 + row] = v1.w;
        Ws[(cb + 0) * 132 + row] = u0.x; Ws[(cb + 1) * 132 + row] = u0.y;
        Ws[(cb + 2) * 132 + row] = u0.z; Ws[(cb + 3) * 132 + row] = u0.w;
        Ws[(cb + 4) * 132 + row] = u1.x; Ws[(cb + 5) * 132 + row] = u1.y;
        Ws[(cb + 6) * 132 + row] = u1.z; Ws[(cb + 7) * 132 + row] = u1.w;
        __syncthreads();
#pragma unroll
        for (int cc = 0; cc < 16; ++cc) {
            const float4* Ap = (const float4*)(As + cc * 132);
            const float4* Wp = (const float4*)(Ws + cc * 132);
            float4 a0 = Ap[ty], a1 = Ap[ty + 16];
            float4 w0 = Wp[tx], w1 = Wp[tx + 16];
            float av[8] = {a0.x, a0.y, a0.z, a0.w, a1.x, a1.y, a1.z, a1.w};
            float wv[8] = {w0.x, w0.y, w0.z, w0.w, w1.x, w1.y, w1.z, w1.w};
#pragma unroll
            for (int i = 0; i < 8; ++i)
#pragma unroll
                for (int j = 0; j < 8; ++j)
                    acc[i][j] += av[i] * wv[j];
        }
    }

#pragma unroll
    for (int j = 0; j < 8; ++j) {
        float mm = acc[0][j];
#pragma unroll
        for (int i = 1; i < 8; ++i) mm = fmaxf(mm, acc[i][j]);
        const int o = (j < 4) ? tx * 4 + j : 64 + tx * 4 + (j - 4);
        red[ty * 128 + o] = mm;
    }
    __syncthreads();
    if (threadIdx.x < 128) {
        const int o = threadIdx.x;
        float mm = red[o];
#pragma unroll
        for (int r = 1; r < 16; ++r) mm = fmaxf(mm, red[r * 128 + o]);
        partial[(size_t)pblk * 1024 + ob * 128 + o] = mm + bias[ob * 128 + o];
    }
}

// ----------------------------------------------------------- final reduce
__global__ __launch_bounds__(256) void reduce_kernel(const float* __restrict__ partial,
                                                     float* __restrict__ out) {
    int t = blockIdx.x * 256 + threadIdx.x;   // 16384
    int b = t >> 10, o = t & 1023;
    float m = -INFINITY;
#pragma unroll 4
    for (int i = 0; i < 16; ++i)
        m = fmaxf(m, partial[(size_t)((b * 16 + i) * 1024) + o]);
    out[t] = m;
}

// ---------------------------------------------------------------- launch
extern "C" void kernel_launch(void* const* d_in, const int* in_sizes, int n_in,
                              void* d_out, int out_size, void* d_ws, size_t ws_size,
                              hipStream_t stream) {
    const float* x = (const float*)d_in[0];
    const float* w_edge = (const float*)d_in[1];
    const float* b_edge = (const float*)d_in[2];
    const float* w1 = (const float*)d_in[3];
    const float* b1 = (const float*)d_in[4];
    const float* w2 = (const float*)d_in[5];
    const float* b2 = (const float*)d_in[6];
    const float* w3 = (const float*)d_in[7];
    const float* b3 = (const float*)d_in[8];
    const float* w_final = (const float*)d_in[9];
    const float* b_final = (const float*)d_in[10];
    float* out = (float*)d_out;

    char* ws = (char*)d_ws;
    int* idx = (int*)ws;                                     // 2,621,440 B
    float* cat = (float*)(ws + 2621440);                     // 67,108,864 B
    float* partial = (float*)(ws + 69730304);                // 1,048,576 B
    double* stats = (double*)(ws + 70778880);                // 8,192 B
    __hip_bfloat16* catb = (__hip_bfloat16*)(ws + 70787072); // 33,554,432 B
    __hip_bfloat16* wb = (__hip_bfloat16*)(ws + 104341504);  // 1,048,576 B
    const size_t WS_NEED = 105390080;
    const bool use_mfma = (ws_size >= WS_NEED);
    __hip_bfloat16* catb_arg = use_mfma ? catb : (__hip_bfloat16*)0;

    double* st_e = stats;
    double* st_1 = stats + 128;
    double* st_2 = stats + 256;
    double* st_3 = stats + 512;

    hipMemsetAsync(stats, 0, 1024 * sizeof(double), stream);
    if (use_mfma)
        wconv_kernel<<<2048, 256, 0, stream>>>(w_final, wb);

    knn_kernel<<<B_ * 64, 256, 0, stream>>>(x, idx);
    edge_kernel<<<B_ * 32, 256, 0, stream>>>(x, idx, w_edge, b_edge, cat, st_e);
    bn_kernel<<<(B_ * N_ * 64) / 256, 256, 0, stream>>>(cat, catb_arg, st_e, 64, 0,
                                                        1.0 / ((double)B_ * N_ * KNN));
    layer_kernel<64, 64, 16><<<(B_ * N_) / 64, 256, 0, stream>>>(cat, idx, w1, b1, st_1, 0, 64);
    bn_kernel<<<(B_ * N_ * 64) / 256, 256, 0, stream>>>(cat, catb_arg, st_1, 64, 64,
                                                        1.0 / ((double)B_ * N_));
    layer_kernel<64, 128, 16><<<(B_ * N_) / 32, 256, 0, stream>>>(cat, idx, w2, b2, st_2, 64, 128);
    bn_kernel<<<(B_ * N_ * 128) / 256, 256, 0, stream>>>(cat, catb_arg, st_2, 128, 128,
                                                         1.0 / ((double)B_ * N_));
    layer_kernel<128, 256, 16><<<(B_ * N_) / 16, 256, 0, stream>>>(cat, idx, w3, b3, st_3, 128, 256);
    bn_kernel<<<(B_ * N_ * 256) / 256, 256, 0, stream>>>(cat, catb_arg, st_3, 256, 256,
                                                         1.0 / ((double)B_ * N_));
    if (use_mfma)
        final_mfma_kernel<<<dim3(8, 256), 256, 0, stream>>>((const short*)catb, (const short*)wb,
                                                            b_final, partial);
    else
        final_kernel<<<dim3(8, 256), 256, 0, stream>>>(cat, w_final, b_final, partial);
    reduce_kernel<<<64, 256, 0, stream>>>(partial, out);
}

// Round 5
// 505.361 us; speedup vs baseline: 3.8383x; 1.4468x over previous
//
#include <hip/hip_runtime.h>
#include <hip/hip_bf16.h>
#include <math.h>

#define B_ 16
#define N_ 2048
#define KNN 20
#define SLOPE 0.2f
#define EPS_ 1e-5f

#define SEG 8
#define SEGLEN (N_ / SEG)   // 256
#define QPB 32              // queries per block
#define CAP 64              // collected-candidate capacity per query

typedef __attribute__((ext_vector_type(8))) short short8;
typedef __attribute__((ext_vector_type(4))) float float4v;

// ---------------------------------------------------------------- kNN
// Order-invariant top-20 set via conservative threshold + collect:
//  scan1: branch-free chunk-max tournament (no insert ladder, no divergence)
//  thresh: 20th largest of 24 conservative samples per query
//  scan2: collect d >= t into LDS list (~25 entries), exact ladder on that.
__global__ __launch_bounds__(256, 3) void knn_kernel(const float* __restrict__ x,
                                                     int* __restrict__ idx) {
    __shared__ float4 pts4[N_];          // 32 KB: x,y,z,|p|^2
    __shared__ float thr[QPB * 24];      // 3 KB: scan-1 samples
    __shared__ float tq[QPB];
    __shared__ int cnt[QPB];
    __shared__ float lv[QPB * CAP];      // 8 KB
    __shared__ int   li[QPB * CAP];      // 8 KB

    const int b = blockIdx.x >> 6;       // 64 blocks per batch
    const int qb = blockIdx.x & 63;
    const float* xb = x + (size_t)b * N_ * 3;
    for (int i = threadIdx.x; i < N_; i += 256) {
        float xv = xb[i * 3], yv = xb[i * 3 + 1], zv = xb[i * 3 + 2];
        pts4[i] = make_float4(xv, yv, zv, xv * xv + yv * yv + zv * zv);
    }
    if (threadIdx.x < QPB) cnt[threadIdx.x] = 0;
    __syncthreads();

    const int s = threadIdx.x >> 5;      // segment 0..7
    const int q = threadIdx.x & 31;      // query within block
    const int n = qb * QPB + q;
    const float4 pq = pts4[n];
    const float px = pq.x, py = pq.y, pz = pq.z, sqn = pq.w;
    const int m0 = s * SEGLEN;
    const int rot = s * 9;               // de-alias half-wave broadcast banks

    // ---- scan 1: 8 chunk-maxes of 32, fully branch-free
    float cmax[8];
#pragma unroll
    for (int c = 0; c < 8; ++c) {
        float vm = -INFINITY;
        for (int i = 0; i < 32; ++i) {
            const int m = m0 + ((c * 32 + i + rot) & (SEGLEN - 1));
            const float4 p = pts4[m];
            const float d = 2.f * (px * p.x + py * p.y + pz * p.z) - sqn - p.w;
            vm = fmaxf(vm, d);
        }
        cmax[c] = vm;
    }
    // top-3 of the 8 chunk maxes (branch-free carried min/max)
    float t0 = -INFINITY, t1 = -INFINITY, t2 = -INFINITY;
#pragma unroll
    for (int c = 0; c < 8; ++c) {
        float v = cmax[c];
        float r0 = fminf(t0, v); t0 = fmaxf(t0, v);
        float r1 = fminf(t1, r0); t1 = fmaxf(t1, r0);
        t2 = fmaxf(t2, r1);
    }
    thr[q * 24 + s * 3 + 0] = t0;
    thr[q * 24 + s * 3 + 1] = t1;
    thr[q * 24 + s * 3 + 2] = t2;
    __syncthreads();

    // ---- threshold: 20th largest of 24 = 5th smallest; conservative epsilon
    if (threadIdx.x < QPB) {
        const int qq = threadIdx.x;
        float s0 = INFINITY, s1 = INFINITY, s2 = INFINITY, s3 = INFINITY, s4 = INFINITY;
#pragma unroll
        for (int j = 0; j < 24; ++j) {
            float c = thr[qq * 24 + j];
            float u;
            u = fminf(s0, c); c = fmaxf(s0, c); s0 = u;
            u = fminf(s1, c); c = fmaxf(s1, c); s1 = u;
            u = fminf(s2, c); c = fmaxf(s2, c); s2 = u;
            u = fminf(s3, c); c = fmaxf(s3, c); s3 = u;
            s4 = fminf(s4, c);
        }
        tq[qq] = s4 - (fabsf(s4) * 1e-6f + 1e-6f);
    }
    __syncthreads();

    // ---- scan 2: collect candidates >= t
    const float t = tq[q];
    for (int i = 0; i < SEGLEN; ++i) {
        const int m = m0 + ((i + rot) & (SEGLEN - 1));
        const float4 p = pts4[m];
        const float d = 2.f * (px * p.x + py * p.y + pz * p.z) - sqn - p.w;
        if (d >= t) {
            int pos = atomicAdd(&cnt[q], 1);
            if (pos < CAP) { lv[q * CAP + pos] = d; li[q * CAP + pos] = m; }
        }
    }
    __syncthreads();

    // ---- exact top-20 per query
    if (threadIdx.x < QPB) {
        const int qq = threadIdx.x;
        const int nn = qb * QPB + qq;
        int* op = idx + (size_t)(b * N_ + nn) * KNN;
        float vals[KNN]; int inds[KNN];
#pragma unroll
        for (int j = 0; j < KNN; ++j) { vals[j] = -INFINITY; inds[j] = 0; }
        const int c = cnt[qq];
        if (c <= CAP) {
            for (int j = 0; j < c; ++j) {
                const float v = lv[qq * CAP + j];
                if (v > vals[KNN - 1]) {
                    float cv = v; int ci = li[qq * CAP + j];
#pragma unroll
                    for (int k = 0; k < KNN; ++k) {
                        const bool sw = cv > vals[k];
                        const float tv = vals[k]; const int ti = inds[k];
                        vals[k] = sw ? cv : tv;  inds[k] = sw ? ci : ti;
                        cv      = sw ? tv : cv;  ci      = sw ? ti : ci;
                    }
                }
            }
        } else {
            // overflow fallback: exact full rescan (rare)
            const float4 pq2 = pts4[nn];
            for (int m = 0; m < N_; ++m) {
                const float4 p = pts4[m];
                const float d = 2.f * (pq2.x * p.x + pq2.y * p.y + pq2.z * p.z)
                                - pq2.w - p.w;
                if (d > vals[KNN - 1]) {
                    float cv = d; int ci = m;
#pragma unroll
                    for (int k = 0; k < KNN; ++k) {
                        const bool sw = cv > vals[k];
                        const float tv = vals[k]; const int ti = inds[k];
                        vals[k] = sw ? cv : tv;  inds[k] = sw ? ci : ti;
                        cv      = sw ? tv : cv;  ci      = sw ? ti : ci;
                    }
                }
            }
        }
#pragma unroll
        for (int j = 0; j < KNN; ++j) op[j] = inds[j];
    }
}

// ------------------------------------------------------------ EdgeConv
__global__ __launch_bounds__(256) void edge_kernel(const float* __restrict__ x,
                                                   const int* __restrict__ idx,
                                                   const float* __restrict__ w_edge,
                                                   const float* __restrict__ b_edge,
                                                   float* __restrict__ cat,
                                                   double* __restrict__ stats) {
    __shared__ float xs[N_ * 3];
    __shared__ float ws[64 * 6];
    __shared__ float bs[64];
    __shared__ float s_sum[64], s_sq[64];

    int b = blockIdx.x >> 5;
    int pb = blockIdx.x & 31;
    const float* xb = x + (size_t)b * N_ * 3;
    for (int i = threadIdx.x; i < N_ * 3; i += 256) xs[i] = xb[i];
    for (int i = threadIdx.x; i < 64 * 6; i += 256) ws[i] = w_edge[i];
    if (threadIdx.x < 64) {
        bs[threadIdx.x] = b_edge[threadIdx.x];
        s_sum[threadIdx.x] = 0.f; s_sq[threadIdx.x] = 0.f;
    }
    __syncthreads();

    int p = threadIdx.x >> 2;
    int cg = threadIdx.x & 3;
    int n = pb * 64 + p;
    float cx = xs[n * 3], cy = xs[n * 3 + 1], cz = xs[n * 3 + 2];

    float maxv[16], sum[16], sq[16];
#pragma unroll
    for (int i = 0; i < 16; ++i) { maxv[i] = -INFINITY; sum[i] = 0.f; sq[i] = 0.f; }

    const int* ip = idx + (size_t)(b * N_ + n) * KNN;
    for (int k = 0; k < KNN; ++k) {
        int j = ip[k];
        float dx = xs[j * 3] - cx, dy = xs[j * 3 + 1] - cy, dz = xs[j * 3 + 2] - cz;
#pragma unroll
        for (int i = 0; i < 16; ++i) {
            int o = cg * 16 + i;
            const float* wr = &ws[o * 6];
            float h = bs[o] + wr[0] * dx + wr[1] * dy + wr[2] * dz
                            + wr[3] * cx + wr[4] * cy + wr[5] * cz;
            sum[i] += h; sq[i] += h * h;
            maxv[i] = fmaxf(maxv[i], h);
        }
    }

    float* cp = cat + (size_t)(b * N_ + n) * 512;
#pragma unroll
    for (int i = 0; i < 16; ++i) {
        int o = cg * 16 + i;
        cp[o] = maxv[i];
        atomicAdd(&s_sum[o], sum[i]);
        atomicAdd(&s_sq[o], sq[i]);
    }
    __syncthreads();
    if (threadIdx.x < 64) {
        atomicAdd(&stats[threadIdx.x], (double)s_sum[threadIdx.x]);
        atomicAdd(&stats[64 + threadIdx.x], (double)s_sq[threadIdx.x]);
    }
}

// ------------------------- BN + LeakyReLU (in place) + bf16 mirror copy
__global__ __launch_bounds__(256) void bn_kernel(float* __restrict__ cat,
                                                 __hip_bfloat16* __restrict__ catb,
                                                 const double* __restrict__ stats,
                                                 int C, int off, double invcnt) {
    int t = blockIdx.x * 256 + threadIdx.x;
    int c = t % C;
    int pn = t / C;
    double meand = stats[c] * invcnt;
    double ex2 = stats[C + c] * invcnt;
    float var = (float)(ex2 - meand * meand);
    float mean = (float)meand;
    float inv = rsqrtf(var + EPS_);
    size_t o = (size_t)pn * 512 + off + c;
    float v = (cat[o] - mean) * inv;
    v = v >= 0.f ? v : SLOPE * v;
    cat[o] = v;
    if (catb) catb[o] = __float2bfloat16(v);
}

// ----------------------------------------------------- w_final -> bf16
__global__ __launch_bounds__(256) void wconv_kernel(const float* __restrict__ w,
                                                    __hip_bfloat16* __restrict__ wb) {
    int t = blockIdx.x * 256 + threadIdx.x;   // 1024*512
    wb[t] = __float2bfloat16(w[t]);
}

// -------------------------------- graph max-pool + 1x1 conv + stats (fused)
template <int CIN, int COUT, int PPT>
__global__ __launch_bounds__(256) void layer_kernel(float* __restrict__ cat,
                                                    const int* __restrict__ idx,
                                                    const float* __restrict__ w,
                                                    const float* __restrict__ bias,
                                                    double* __restrict__ stats,
                                                    int off_in, int off_out) {
    constexpr int PG = 256 / COUT;
    constexpr int P = PG * PPT;
    constexpr int PPAR = 256 / CIN;

    __shared__ float g[P * CIN];
    __shared__ float wt[COUT * 17];
    __shared__ float s_sum[COUT], s_sq[COUT];

    int pt0 = blockIdx.x * P;
    int b = pt0 / N_;

    {
        int c = threadIdx.x % CIN;
        int pp = threadIdx.x / CIN;
        for (int p = pp; p < P; p += PPAR) {
            const int* ip = idx + (size_t)(pt0 + p) * KNN;
            float m = -INFINITY;
#pragma unroll
            for (int k = 0; k < KNN; ++k) {
                int j = ip[k];
                m = fmaxf(m, cat[(size_t)(b * N_ + j) * 512 + off_in + c]);
            }
            g[p * CIN + c] = m;
        }
    }
    if (threadIdx.x < COUT) { s_sum[threadIdx.x] = 0.f; s_sq[threadIdx.x] = 0.f; }
    __syncthreads();

    int ot = threadIdx.x % COUT;
    int pg = threadIdx.x / COUT;
    float acc[PPT];
#pragma unroll
    for (int i = 0; i < PPT; ++i) acc[i] = 0.f;

    for (int c0 = 0; c0 < CIN; c0 += 16) {
        __syncthreads();
        for (int i = threadIdx.x; i < COUT * 16; i += 256) {
            int o = i >> 4, cc = i & 15;
            wt[o * 17 + cc] = w[(size_t)o * CIN + c0 + cc];
        }
        __syncthreads();
#pragma unroll
        for (int cc = 0; cc < 16; ++cc) {
            float wv = wt[ot * 17 + cc];
#pragma unroll
            for (int i = 0; i < PPT; ++i)
                acc[i] += wv * g[(pg + i * PG) * CIN + c0 + cc];
        }
    }

    float bo = bias[ot];
    float lsum = 0.f, lsq = 0.f;
#pragma unroll
    for (int i = 0; i < PPT; ++i) {
        float h = acc[i] + bo;
        lsum += h; lsq += h * h;
        cat[(size_t)(pt0 + pg + i * PG) * 512 + off_out + ot] = h;
    }
    atomicAdd(&s_sum[ot], lsum);
    atomicAdd(&s_sq[ot], lsq);
    __syncthreads();
    if (threadIdx.x < COUT) {
        atomicAdd(&stats[threadIdx.x], (double)s_sum[threadIdx.x]);
        atomicAdd(&stats[COUT + threadIdx.x], (double)s_sq[threadIdx.x]);
    }
}

// -------------- final GEMM via bf16 MFMA + bias + max-over-n (register staging)
__global__ __launch_bounds__(256) void final_mfma_kernel(const short* __restrict__ catb,
                                                         const short* __restrict__ wb,
                                                         const float* __restrict__ bias,
                                                         float* __restrict__ partial) {
    constexpr int LDK = 72;              // 64 + 8 pad: 144 B row stride (16B-aligned)
    __shared__ short As[128 * LDK];
    __shared__ short Bs[128 * LDK];
    __shared__ float red[256];

    const int ob = blockIdx.x;     // 0..7, fast-varying: A tile stays L2/LLC-hot
    const int pblk = blockIdx.y;   // 0..255
    const int pt0 = pblk * 128;

    const int wid = threadIdx.x >> 6;
    const int lane = threadIdx.x & 63;
    const int wm = wid >> 1, wn = wid & 1;   // 2x2 wave grid -> 64x64 per wave
    const int lm = lane & 15, g = lane >> 4;

    const int srow = threadIdx.x >> 1;
    const int scg = (threadIdx.x & 1) * 32;
    const short* ga = catb + (size_t)(pt0 + srow) * 512 + scg;
    const short* gb = wb + (size_t)(ob * 128 + srow) * 512 + scg;
    short* la = As + srow * LDK + scg;
    short* lb = Bs + srow * LDK + scg;

    float4v acc[4][4];
#pragma unroll
    for (int i = 0; i < 4; ++i)
#pragma unroll
        for (int j = 0; j < 4; ++j) acc[i][j] = {0.f, 0.f, 0.f, 0.f};

    short8 ra[4], rb[4];
#pragma unroll
    for (int j = 0; j < 4; ++j) {
        ra[j] = *(const short8*)(ga + j * 8);
        rb[j] = *(const short8*)(gb + j * 8);
    }

    for (int step = 0; step < 8; ++step) {
        __syncthreads();
#pragma unroll
        for (int j = 0; j < 4; ++j) {
            *(short8*)(la + j * 8) = ra[j];
            *(short8*)(lb + j * 8) = rb[j];
        }
        __syncthreads();
        if (step < 7) {
            const int c1 = (step + 1) * 64;
#pragma unroll
            for (int j = 0; j < 4; ++j) {
                ra[j] = *(const short8*)(ga + c1 + j * 8);
                rb[j] = *(const short8*)(gb + c1 + j * 8);
            }
        }
#pragma unroll
        for (int kk = 0; kk < 2; ++kk) {
            short8 a[4], b[4];
#pragma unroll
            for (int t = 0; t < 4; ++t) {
                a[t] = *(const short8*)&As[(wm * 64 + t * 16 + lm) * LDK + kk * 32 + g * 8];
                b[t] = *(const short8*)&Bs[(wn * 64 + t * 16 + lm) * LDK + kk * 32 + g * 8];
            }
#pragma unroll
            for (int mt = 0; mt < 4; ++mt)
#pragma unroll
                for (int nt = 0; nt < 4; ++nt)
                    acc[mt][nt] = __builtin_amdgcn_mfma_f32_16x16x32_bf16(
                        a[mt], b[nt], acc[mt][nt], 0, 0, 0);
        }
    }

    float cm[4];
#pragma unroll
    for (int nt = 0; nt < 4; ++nt) {
        float m = -INFINITY;
#pragma unroll
        for (int mt = 0; mt < 4; ++mt)
#pragma unroll
            for (int r = 0; r < 4; ++r) m = fmaxf(m, acc[mt][nt][r]);
        m = fmaxf(m, __shfl_xor(m, 16, 64));
        m = fmaxf(m, __shfl_xor(m, 32, 64));
        cm[nt] = m;
    }
    __syncthreads();
    if (lane < 16) {
#pragma unroll
        for (int nt = 0; nt < 4; ++nt)
            red[wm * 128 + wn * 64 + nt * 16 + lane] = cm[nt];
    }
    __syncthreads();
    if (threadIdx.x < 128) {
        const int o = threadIdx.x;
        float v = fmaxf(red[o], red[128 + o]) + bias[ob * 128 + o];
        partial[(size_t)pblk * 1024 + ob * 128 + o] = v;
    }
}

// ---------------------- fp32 fallback final GEMM (if workspace too small)
__global__ __launch_bounds__(256) void final_kernel(const float* __restrict__ cat,
                                                    const float* __restrict__ w,
                                                    const float* __restrict__ bias,
                                                    float* __restrict__ partial) {
    __shared__ float As[16 * 132];
    __shared__ float Ws[16 * 132];
    __shared__ float red[16 * 128];

    const int ob = blockIdx.x;
    const int pblk = blockIdx.y;
    const int pt0 = pblk * 128;
    const int tx = threadIdx.x & 15;
    const int ty = threadIdx.x >> 4;

    float acc[8][8];
#pragma unroll
    for (int i = 0; i < 8; ++i)
#pragma unroll
        for (int j = 0; j < 8; ++j) acc[i][j] = 0.f;

    const int row = threadIdx.x & 127;
    const int half = threadIdx.x >> 7;
    const float* arow = cat + (size_t)(pt0 + row) * 512 + half * 8;
    const float* wrow = w + (size_t)(ob * 128 + row) * 512 + half * 8;

    for (int c0 = 0; c0 < 512; c0 += 16) {
        __syncthreads();
        float4 v0 = *(const float4*)(arow + c0);
        float4 v1 = *(const float4*)(arow + c0 + 4);
        float4 u0 = *(const float4*)(wrow + c0);
        float4 u1 = *(const float4*)(wrow + c0 + 4);
        const int cb = half * 8;
        As[(cb + 0) * 132 + row] = v0.x; As[(cb + 1) * 132 + row] = v0.y;
        As[(cb + 2) * 132 + row] = v0.z; As[(cb + 3) * 132 + row] = v0.w;
        As[(cb + 4) * 132 + row] = v1.x; As[(cb + 5) * 132 + row] = v1.y;
        As[(cb + 6) * 132 + row] = v1.z; As[(cb + 7) * 132 + row] = v1.w;
        Ws[(cb + 0) * 132 + row] = u0.x; Ws[(cb + 1) * 132 + row] = u0.y;
        Ws[(cb + 2) * 132 + row] = u0.z; Ws[(cb + 3) * 132 + row] = u0.w;
        Ws[(cb + 4) * 132 + row] = u1.x; Ws[(cb + 5) * 132 + row] = u1.y;
        Ws[(cb + 6) * 132 + row] = u1.z; Ws[(cb + 7) * 132 + row] = u1.w;
        __syncthreads();
#pragma unroll
        for (int cc = 0; cc < 16; ++cc) {
            const float4* Ap = (const float4*)(As + cc * 132);
            const float4* Wp = (const float4*)(Ws + cc * 132);
            float4 a0 = Ap[ty], a1 = Ap[ty + 16];
            float4 w0 = Wp[tx], w1 = Wp[tx + 16];
            float av[8] = {a0.x, a0.y, a0.z, a0.w, a1.x, a1.y, a1.z, a1.w};
            float wv[8] = {w0.x, w0.y, w0.z, w0.w, w1.x, w1.y, w1.z, w1.w};
#pragma unroll
            for (int i = 0; i < 8; ++i)
#pragma unroll
                for (int j = 0; j < 8; ++j)
                    acc[i][j] += av[i] * wv[j];
        }
    }

#pragma unroll
    for (int j = 0; j < 8; ++j) {
        float mm = acc[0][j];
#pragma unroll
        for (int i = 1; i < 8; ++i) mm = fmaxf(mm, acc[i][j]);
        const int o = (j < 4) ? tx * 4 + j : 64 + tx * 4 + (j - 4);
        red[ty * 128 + o] = mm;
    }
    __syncthreads();
    if (threadIdx.x < 128) {
        const int o = threadIdx.x;
        float mm = red[o];
#pragma unroll
        for (int r = 1; r < 16; ++r) mm = fmaxf(mm, red[r * 128 + o]);
        partial[(size_t)pblk * 1024 + ob * 128 + o] = mm + bias[ob * 128 + o];
    }
}

// ----------------------------------------------------------- final reduce
__global__ __launch_bounds__(256) void reduce_kernel(const float* __restrict__ partial,
                                                     float* __restrict__ out) {
    int t = blockIdx.x * 256 + threadIdx.x;   // 16384
    int b = t >> 10, o = t & 1023;
    float m = -INFINITY;
#pragma unroll 4
    for (int i = 0; i < 16; ++i)
        m = fmaxf(m, partial[(size_t)((b * 16 + i) * 1024) + o]);
    out[t] = m;
}

// ---------------------------------------------------------------- launch
extern "C" void kernel_launch(void* const* d_in, const int* in_sizes, int n_in,
                              void* d_out, int out_size, void* d_ws, size_t ws_size,
                              hipStream_t stream) {
    const float* x = (const float*)d_in[0];
    const float* w_edge = (const float*)d_in[1];
    const float* b_edge = (const float*)d_in[2];
    const float* w1 = (const float*)d_in[3];
    const float* b1 = (const float*)d_in[4];
    const float* w2 = (const float*)d_in[5];
    const float* b2 = (const float*)d_in[6];
    const float* w3 = (const float*)d_in[7];
    const float* b3 = (const float*)d_in[8];
    const float* w_final = (const float*)d_in[9];
    const float* b_final = (const float*)d_in[10];
    float* out = (float*)d_out;

    char* ws = (char*)d_ws;
    int* idx = (int*)ws;                                     // 2,621,440 B
    float* cat = (float*)(ws + 2621440);                     // 67,108,864 B
    float* partial = (float*)(ws + 69730304);                // 1,048,576 B
    double* stats = (double*)(ws + 70778880);                // 8,192 B
    __hip_bfloat16* catb = (__hip_bfloat16*)(ws + 70787072); // 33,554,432 B
    __hip_bfloat16* wb = (__hip_bfloat16*)(ws + 104341504);  // 1,048,576 B
    const size_t WS_NEED = 105390080;
    const bool use_mfma = (ws_size >= WS_NEED);
    __hip_bfloat16* catb_arg = use_mfma ? catb : (__hip_bfloat16*)0;

    double* st_e = stats;
    double* st_1 = stats + 128;
    double* st_2 = stats + 256;
    double* st_3 = stats + 512;

    hipMemsetAsync(stats, 0, 1024 * sizeof(double), stream);
    if (use_mfma)
        wconv_kernel<<<2048, 256, 0, stream>>>(w_final, wb);

    knn_kernel<<<B_ * 64, 256, 0, stream>>>(x, idx);
    edge_kernel<<<B_ * 32, 256, 0, stream>>>(x, idx, w_edge, b_edge, cat, st_e);
    bn_kernel<<<(B_ * N_ * 64) / 256, 256, 0, stream>>>(cat, catb_arg, st_e, 64, 0,
                                                        1.0 / ((double)B_ * N_ * KNN));
    layer_kernel<64, 64, 16><<<(B_ * N_) / 64, 256, 0, stream>>>(cat, idx, w1, b1, st_1, 0, 64);
    bn_kernel<<<(B_ * N_ * 64) / 256, 256, 0, stream>>>(cat, catb_arg, st_1, 64, 64,
                                                        1.0 / ((double)B_ * N_));
    layer_kernel<64, 128, 16><<<(B_ * N_) / 32, 256, 0, stream>>>(cat, idx, w2, b2, st_2, 64, 128);
    bn_kernel<<<(B_ * N_ * 128) / 256, 256, 0, stream>>>(cat, st_2 ? catb_arg : catb_arg, st_2, 128, 128,
                                                         1.0 / ((double)B_ * N_));
    layer_kernel<128, 256, 16><<<(B_ * N_) / 16, 256, 0, stream>>>(cat, idx, w3, b3, st_3, 128, 256);
    bn_kernel<<<(B_ * N_ * 256) / 256, 256, 0, stream>>>(cat, catb_arg, st_3, 256, 256,
                                                         1.0 / ((double)B_ * N_));
    if (use_mfma)
        final_mfma_kernel<<<dim3(8, 256), 256, 0, stream>>>((const short*)catb, (const short*)wb,
                                                            b_final, partial);
    else
        final_kernel<<<dim3(8, 256), 256, 0, stream>>>(cat, w_final, b_final, partial);
    reduce_kernel<<<64, 256, 0, stream>>>(partial, out);
}

// Round 6
// 466.396 us; speedup vs baseline: 4.1589x; 1.0835x over previous
//
#include <hip/hip_runtime.h>
#include <hip/hip_bf16.h>
#include <math.h>

#define B_ 16
#define N_ 2048
#define KNN 20
#define SLOPE 0.2f
#define EPS_ 1e-5f

#define SEG 8
#define SEGLEN (N_ / SEG)   // 256
#define QPB 64              // queries per block (2 per thread)
#define CAP 64              // collected-candidate capacity per query

typedef __attribute__((ext_vector_type(8))) short short8;
typedef __attribute__((ext_vector_type(4))) float float4v;

// ---------------------------------------------------------------- kNN
// Threshold+collect (validated R5) with 2 queries/thread: each pts4 LDS read
// feeds two distance evals -> LDS b128 traffic halves. 512 blocks = exactly
// 2 resident/CU (72 KB LDS) -> no tail round.
__global__ __launch_bounds__(256, 2) void knn_kernel(const float* __restrict__ x,
                                                     int* __restrict__ idx) {
    __shared__ float4 pts4[N_];          // 32 KB: x,y,z,|p|^2
    __shared__ float thr[QPB * 24];      // 6 KB: scan-1 samples
    __shared__ float tq[QPB];
    __shared__ int cnt[QPB];
    __shared__ float lv[QPB * CAP];      // 16 KB
    __shared__ int   li[QPB * CAP];      // 16 KB

    const int b = blockIdx.x >> 5;       // 32 blocks per batch
    const int qb = blockIdx.x & 31;
    const float* xb = x + (size_t)b * N_ * 3;
    for (int i = threadIdx.x; i < N_; i += 256) {
        float xv = xb[i * 3], yv = xb[i * 3 + 1], zv = xb[i * 3 + 2];
        pts4[i] = make_float4(xv, yv, zv, xv * xv + yv * yv + zv * zv);
    }
    if (threadIdx.x < QPB) cnt[threadIdx.x] = 0;
    __syncthreads();

    const int s = threadIdx.x >> 5;      // segment 0..7 (uniform per half-wave)
    const int qs = threadIdx.x & 31;     // query-pair slot
    const int q0 = qs * 2, q1 = q0 + 1;
    const int n0 = qb * QPB + q0;
    const float4 pa = pts4[n0];
    const float4 pb = pts4[n0 + 1];
    const int m0 = s * SEGLEN;
    const int rot = s * 9;               // de-alias half-wave broadcast banks

    // ---- scan 1: 8 chunk-maxes of 32 per query, fully branch-free
    float ca[8], cb[8];
#pragma unroll
    for (int c = 0; c < 8; ++c) {
        float va = -INFINITY, vb = -INFINITY;
        for (int i = 0; i < 32; ++i) {
            const int m = m0 + ((c * 32 + i + rot) & (SEGLEN - 1));
            const float4 p = pts4[m];
            va = fmaxf(va, 2.f * (pa.x * p.x + pa.y * p.y + pa.z * p.z) - pa.w - p.w);
            vb = fmaxf(vb, 2.f * (pb.x * p.x + pb.y * p.y + pb.z * p.z) - pb.w - p.w);
        }
        ca[c] = va; cb[c] = vb;
    }
    // top-3 of the 8 chunk maxes per query (branch-free carried min/max)
    {
        float t0 = -INFINITY, t1 = -INFINITY, t2 = -INFINITY;
        float u0 = -INFINITY, u1 = -INFINITY, u2 = -INFINITY;
#pragma unroll
        for (int c = 0; c < 8; ++c) {
            float v = ca[c];
            float r0 = fminf(t0, v); t0 = fmaxf(t0, v);
            float r1 = fminf(t1, r0); t1 = fmaxf(t1, r0);
            t2 = fmaxf(t2, r1);
            float w = cb[c];
            float s0 = fminf(u0, w); u0 = fmaxf(u0, w);
            float s1 = fminf(u1, s0); u1 = fmaxf(u1, s0);
            u2 = fmaxf(u2, s1);
        }
        thr[q0 * 24 + s * 3 + 0] = t0;
        thr[q0 * 24 + s * 3 + 1] = t1;
        thr[q0 * 24 + s * 3 + 2] = t2;
        thr[q1 * 24 + s * 3 + 0] = u0;
        thr[q1 * 24 + s * 3 + 1] = u1;
        thr[q1 * 24 + s * 3 + 2] = u2;
    }
    __syncthreads();

    // ---- threshold: 20th largest of 24 = 5th smallest; conservative epsilon
    if (threadIdx.x < QPB) {
        const int qq = threadIdx.x;
        float s0 = INFINITY, s1 = INFINITY, s2 = INFINITY, s3 = INFINITY, s4 = INFINITY;
#pragma unroll
        for (int j = 0; j < 24; ++j) {
            float c = thr[qq * 24 + j];
            float u;
            u = fminf(s0, c); c = fmaxf(s0, c); s0 = u;
            u = fminf(s1, c); c = fmaxf(s1, c); s1 = u;
            u = fminf(s2, c); c = fmaxf(s2, c); s2 = u;
            u = fminf(s3, c); c = fmaxf(s3, c); s3 = u;
            s4 = fminf(s4, c);
        }
        tq[qq] = s4 - (fabsf(s4) * 1e-6f + 1e-6f);
    }
    __syncthreads();

    // ---- scan 2: collect candidates >= t for both queries
    const float ta = tq[q0];
    const float tb = tq[q1];
    for (int i = 0; i < SEGLEN; ++i) {
        const int m = m0 + ((i + rot) & (SEGLEN - 1));
        const float4 p = pts4[m];
        const float da = 2.f * (pa.x * p.x + pa.y * p.y + pa.z * p.z) - pa.w - p.w;
        const float db = 2.f * (pb.x * p.x + pb.y * p.y + pb.z * p.z) - pb.w - p.w;
        if (da >= ta) {
            int pos = atomicAdd(&cnt[q0], 1);
            if (pos < CAP) { lv[q0 * CAP + pos] = da; li[q0 * CAP + pos] = m; }
        }
        if (db >= tb) {
            int pos = atomicAdd(&cnt[q1], 1);
            if (pos < CAP) { lv[q1 * CAP + pos] = db; li[q1 * CAP + pos] = m; }
        }
    }
    __syncthreads();

    // ---- exact top-20 per query
    if (threadIdx.x < QPB) {
        const int qq = threadIdx.x;
        const int nn = qb * QPB + qq;
        int* op = idx + (size_t)(b * N_ + nn) * KNN;
        float vals[KNN]; int inds[KNN];
#pragma unroll
        for (int j = 0; j < KNN; ++j) { vals[j] = -INFINITY; inds[j] = 0; }
        const int c = cnt[qq];
        if (c <= CAP) {
            for (int j = 0; j < c; ++j) {
                const float v = lv[qq * CAP + j];
                if (v > vals[KNN - 1]) {
                    float cv = v; int ci = li[qq * CAP + j];
#pragma unroll
                    for (int k = 0; k < KNN; ++k) {
                        const bool sw = cv > vals[k];
                        const float tv = vals[k]; const int ti = inds[k];
                        vals[k] = sw ? cv : tv;  inds[k] = sw ? ci : ti;
                        cv      = sw ? tv : cv;  ci      = sw ? ti : ci;
                    }
                }
            }
        } else {
            // overflow fallback: exact full rescan (rare)
            const float4 pq2 = pts4[nn];
            for (int m = 0; m < N_; ++m) {
                const float4 p = pts4[m];
                const float d = 2.f * (pq2.x * p.x + pq2.y * p.y + pq2.z * p.z)
                                - pq2.w - p.w;
                if (d > vals[KNN - 1]) {
                    float cv = d; int ci = m;
#pragma unroll
                    for (int k = 0; k < KNN; ++k) {
                        const bool sw = cv > vals[k];
                        const float tv = vals[k]; const int ti = inds[k];
                        vals[k] = sw ? cv : tv;  inds[k] = sw ? ci : ti;
                        cv      = sw ? tv : cv;  ci      = sw ? ti : ci;
                    }
                }
            }
        }
#pragma unroll
        for (int j = 0; j < KNN; ++j) op[j] = inds[j];
    }
}

// ------------------------------------------------------------ EdgeConv
__global__ __launch_bounds__(256) void edge_kernel(const float* __restrict__ x,
                                                   const int* __restrict__ idx,
                                                   const float* __restrict__ w_edge,
                                                   const float* __restrict__ b_edge,
                                                   float* __restrict__ cat,
                                                   double* __restrict__ stats) {
    __shared__ float xs[N_ * 3];
    __shared__ float ws[64 * 6];
    __shared__ float bs[64];
    __shared__ float s_sum[64], s_sq[64];

    int b = blockIdx.x >> 5;
    int pb = blockIdx.x & 31;
    const float* xb = x + (size_t)b * N_ * 3;
    for (int i = threadIdx.x; i < N_ * 3; i += 256) xs[i] = xb[i];
    for (int i = threadIdx.x; i < 64 * 6; i += 256) ws[i] = w_edge[i];
    if (threadIdx.x < 64) {
        bs[threadIdx.x] = b_edge[threadIdx.x];
        s_sum[threadIdx.x] = 0.f; s_sq[threadIdx.x] = 0.f;
    }
    __syncthreads();

    int p = threadIdx.x >> 2;
    int cg = threadIdx.x & 3;
    int n = pb * 64 + p;
    float cx = xs[n * 3], cy = xs[n * 3 + 1], cz = xs[n * 3 + 2];

    float maxv[16], sum[16], sq[16];
#pragma unroll
    for (int i = 0; i < 16; ++i) { maxv[i] = -INFINITY; sum[i] = 0.f; sq[i] = 0.f; }

    const int* ip = idx + (size_t)(b * N_ + n) * KNN;
    for (int k = 0; k < KNN; ++k) {
        int j = ip[k];
        float dx = xs[j * 3] - cx, dy = xs[j * 3 + 1] - cy, dz = xs[j * 3 + 2] - cz;
#pragma unroll
        for (int i = 0; i < 16; ++i) {
            int o = cg * 16 + i;
            const float* wr = &ws[o * 6];
            float h = bs[o] + wr[0] * dx + wr[1] * dy + wr[2] * dz
                            + wr[3] * cx + wr[4] * cy + wr[5] * cz;
            sum[i] += h; sq[i] += h * h;
            maxv[i] = fmaxf(maxv[i], h);
        }
    }

    float* cp = cat + (size_t)(b * N_ + n) * 512;
#pragma unroll
    for (int i = 0; i < 16; ++i) {
        int o = cg * 16 + i;
        cp[o] = maxv[i];
        atomicAdd(&s_sum[o], sum[i]);
        atomicAdd(&s_sq[o], sq[i]);
    }
    __syncthreads();
    if (threadIdx.x < 64) {
        atomicAdd(&stats[threadIdx.x], (double)s_sum[threadIdx.x]);
        atomicAdd(&stats[64 + threadIdx.x], (double)s_sq[threadIdx.x]);
    }
}

// ------------------------- BN + LeakyReLU (in place) + bf16 mirror copy
__global__ __launch_bounds__(256) void bn_kernel(float* __restrict__ cat,
                                                 __hip_bfloat16* __restrict__ catb,
                                                 const double* __restrict__ stats,
                                                 int C, int off, double invcnt) {
    int t = blockIdx.x * 256 + threadIdx.x;
    int c = t % C;
    int pn = t / C;
    double meand = stats[c] * invcnt;
    double ex2 = stats[C + c] * invcnt;
    float var = (float)(ex2 - meand * meand);
    float mean = (float)meand;
    float inv = rsqrtf(var + EPS_);
    size_t o = (size_t)pn * 512 + off + c;
    float v = (cat[o] - mean) * inv;
    v = v >= 0.f ? v : SLOPE * v;
    cat[o] = v;
    if (catb) catb[o] = __float2bfloat16(v);
}

// ----------------------------------------------------- w_final -> bf16
__global__ __launch_bounds__(256) void wconv_kernel(const float* __restrict__ w,
                                                    __hip_bfloat16* __restrict__ wb) {
    int t = blockIdx.x * 256 + threadIdx.x;   // 1024*512
    wb[t] = __float2bfloat16(w[t]);
}

// -------------------------------- graph max-pool + 1x1 conv + stats (fused)
template <int CIN, int COUT, int PPT>
__global__ __launch_bounds__(256) void layer_kernel(float* __restrict__ cat,
                                                    const int* __restrict__ idx,
                                                    const float* __restrict__ w,
                                                    const float* __restrict__ bias,
                                                    double* __restrict__ stats,
                                                    int off_in, int off_out) {
    constexpr int PG = 256 / COUT;
    constexpr int P = PG * PPT;
    constexpr int PPAR = 256 / CIN;

    __shared__ float g[P * CIN];
    __shared__ float wt[COUT * 17];
    __shared__ float s_sum[COUT], s_sq[COUT];

    int pt0 = blockIdx.x * P;
    int b = pt0 / N_;

    {
        int c = threadIdx.x % CIN;
        int pp = threadIdx.x / CIN;
        for (int p = pp; p < P; p += PPAR) {
            const int* ip = idx + (size_t)(pt0 + p) * KNN;
            float m = -INFINITY;
#pragma unroll
            for (int k = 0; k < KNN; ++k) {
                int j = ip[k];
                m = fmaxf(m, cat[(size_t)(b * N_ + j) * 512 + off_in + c]);
            }
            g[p * CIN + c] = m;
        }
    }
    if (threadIdx.x < COUT) { s_sum[threadIdx.x] = 0.f; s_sq[threadIdx.x] = 0.f; }
    __syncthreads();

    int ot = threadIdx.x % COUT;
    int pg = threadIdx.x / COUT;
    float acc[PPT];
#pragma unroll
    for (int i = 0; i < PPT; ++i) acc[i] = 0.f;

    for (int c0 = 0; c0 < CIN; c0 += 16) {
        __syncthreads();
        for (int i = threadIdx.x; i < COUT * 16; i += 256) {
            int o = i >> 4, cc = i & 15;
            wt[o * 17 + cc] = w[(size_t)o * CIN + c0 + cc];
        }
        __syncthreads();
#pragma unroll
        for (int cc = 0; cc < 16; ++cc) {
            float wv = wt[ot * 17 + cc];
#pragma unroll
            for (int i = 0; i < PPT; ++i)
                acc[i] += wv * g[(pg + i * PG) * CIN + c0 + cc];
        }
    }

    float bo = bias[ot];
    float lsum = 0.f, lsq = 0.f;
#pragma unroll
    for (int i = 0; i < PPT; ++i) {
        float h = acc[i] + bo;
        lsum += h; lsq += h * h;
        cat[(size_t)(pt0 + pg + i * PG) * 512 + off_out + ot] = h;
    }
    atomicAdd(&s_sum[ot], lsum);
    atomicAdd(&s_sq[ot], lsq);
    __syncthreads();
    if (threadIdx.x < COUT) {
        atomicAdd(&stats[threadIdx.x], (double)s_sum[threadIdx.x]);
        atomicAdd(&stats[COUT + threadIdx.x], (double)s_sq[threadIdx.x]);
    }
}

// -------------- final GEMM via bf16 MFMA + bias + max-over-n (register staging)
__global__ __launch_bounds__(256) void final_mfma_kernel(const short* __restrict__ catb,
                                                         const short* __restrict__ wb,
                                                         const float* __restrict__ bias,
                                                         float* __restrict__ partial) {
    constexpr int LDK = 72;              // 64 + 8 pad: 144 B row stride (16B-aligned)
    __shared__ short As[128 * LDK];
    __shared__ short Bs[128 * LDK];
    __shared__ float red[256];

    const int ob = blockIdx.x;     // 0..7, fast-varying: A tile stays L2/LLC-hot
    const int pblk = blockIdx.y;   // 0..255
    const int pt0 = pblk * 128;

    const int wid = threadIdx.x >> 6;
    const int lane = threadIdx.x & 63;
    const int wm = wid >> 1, wn = wid & 1;   // 2x2 wave grid -> 64x64 per wave
    const int lm = lane & 15, g = lane >> 4;

    const int srow = threadIdx.x >> 1;
    const int scg = (threadIdx.x & 1) * 32;
    const short* ga = catb + (size_t)(pt0 + srow) * 512 + scg;
    const short* gb = wb + (size_t)(ob * 128 + srow) * 512 + scg;
    short* la = As + srow * LDK + scg;
    short* lb = Bs + srow * LDK + scg;

    float4v acc[4][4];
#pragma unroll
    for (int i = 0; i < 4; ++i)
#pragma unroll
        for (int j = 0; j < 4; ++j) acc[i][j] = {0.f, 0.f, 0.f, 0.f};

    short8 ra[4], rb[4];
#pragma unroll
    for (int j = 0; j < 4; ++j) {
        ra[j] = *(const short8*)(ga + j * 8);
        rb[j] = *(const short8*)(gb + j * 8);
    }

    for (int step = 0; step < 8; ++step) {
        __syncthreads();
#pragma unroll
        for (int j = 0; j < 4; ++j) {
            *(short8*)(la + j * 8) = ra[j];
            *(short8*)(lb + j * 8) = rb[j];
        }
        __syncthreads();
        if (step < 7) {
            const int c1 = (step + 1) * 64;
#pragma unroll
            for (int j = 0; j < 4; ++j) {
                ra[j] = *(const short8*)(ga + c1 + j * 8);
                rb[j] = *(const short8*)(gb + c1 + j * 8);
            }
        }
#pragma unroll
        for (int kk = 0; kk < 2; ++kk) {
            short8 a[4], b[4];
#pragma unroll
            for (int t = 0; t < 4; ++t) {
                a[t] = *(const short8*)&As[(wm * 64 + t * 16 + lm) * LDK + kk * 32 + g * 8];
                b[t] = *(const short8*)&Bs[(wn * 64 + t * 16 + lm) * LDK + kk * 32 + g * 8];
            }
#pragma unroll
            for (int mt = 0; mt < 4; ++mt)
#pragma unroll
                for (int nt = 0; nt < 4; ++nt)
                    acc[mt][nt] = __builtin_amdgcn_mfma_f32_16x16x32_bf16(
                        a[mt], b[nt], acc[mt][nt], 0, 0, 0);
        }
    }

    float cm[4];
#pragma unroll
    for (int nt = 0; nt < 4; ++nt) {
        float m = -INFINITY;
#pragma unroll
        for (int mt = 0; mt < 4; ++mt)
#pragma unroll
            for (int r = 0; r < 4; ++r) m = fmaxf(m, acc[mt][nt][r]);
        m = fmaxf(m, __shfl_xor(m, 16, 64));
        m = fmaxf(m, __shfl_xor(m, 32, 64));
        cm[nt] = m;
    }
    __syncthreads();
    if (lane < 16) {
#pragma unroll
        for (int nt = 0; nt < 4; ++nt)
            red[wm * 128 + wn * 64 + nt * 16 + lane] = cm[nt];
    }
    __syncthreads();
    if (threadIdx.x < 128) {
        const int o = threadIdx.x;
        float v = fmaxf(red[o], red[128 + o]) + bias[ob * 128 + o];
        partial[(size_t)pblk * 1024 + ob * 128 + o] = v;
    }
}

// ---------------------- fp32 fallback final GEMM (if workspace too small)
__global__ __launch_bounds__(256) void final_kernel(const float* __restrict__ cat,
                                                    const float* __restrict__ w,
                                                    const float* __restrict__ bias,
                                                    float* __restrict__ partial) {
    __shared__ float As[16 * 132];
    __shared__ float Ws[16 * 132];
    __shared__ float red[16 * 128];

    const int ob = blockIdx.x;
    const int pblk = blockIdx.y;
    const int pt0 = pblk * 128;
    const int tx = threadIdx.x & 15;
    const int ty = threadIdx.x >> 4;

    float acc[8][8];
#pragma unroll
    for (int i = 0; i < 8; ++i)
#pragma unroll
        for (int j = 0; j < 8; ++j) acc[i][j] = 0.f;

    const int row = threadIdx.x & 127;
    const int half = threadIdx.x >> 7;
    const float* arow = cat + (size_t)(pt0 + row) * 512 + half * 8;
    const float* wrow = w + (size_t)(ob * 128 + row) * 512 + half * 8;

    for (int c0 = 0; c0 < 512; c0 += 16) {
        __syncthreads();
        float4 v0 = *(const float4*)(arow + c0);
        float4 v1 = *(const float4*)(arow + c0 + 4);
        float4 u0 = *(const float4*)(wrow + c0);
        float4 u1 = *(const float4*)(wrow + c0 + 4);
        const int cb = half * 8;
        As[(cb + 0) * 132 + row] = v0.x; As[(cb + 1) * 132 + row] = v0.y;
        As[(cb + 2) * 132 + row] = v0.z; As[(cb + 3) * 132 + row] = v0.w;
        As[(cb + 4) * 132 + row] = v1.x; As[(cb + 5) * 132 + row] = v1.y;
        As[(cb + 6) * 132 + row] = v1.z; As[(cb + 7) * 132 + row] = v1.w;
        Ws[(cb + 0) * 132 + row] = u0.x; Ws[(cb + 1) * 132 + row] = u0.y;
        Ws[(cb + 2) * 132 + row] = u0.z; Ws[(cb + 3) * 132 + row] = u0.w;
        Ws[(cb + 4) * 132 + row] = u1.x; Ws[(cb + 5) * 132 + row] = u1.y;
        Ws[(cb + 6) * 132 + row] = u1.z; Ws[(cb + 7) * 132 + row] = u1.w;
        __syncthreads();
#pragma unroll
        for (int cc = 0; cc < 16; ++cc) {
            const float4* Ap = (const float4*)(As + cc * 132);
            const float4* Wp = (const float4*)(Ws + cc * 132);
            float4 a0 = Ap[ty], a1 = Ap[ty + 16];
            float4 w0 = Wp[tx], w1 = Wp[tx + 16];
            float av[8] = {a0.x, a0.y, a0.z, a0.w, a1.x, a1.y, a1.z, a1.w};
            float wv[8] = {w0.x, w0.y, w0.z, w0.w, w1.x, w1.y, w1.z, w1.w};
#pragma unroll
            for (int i = 0; i < 8; ++i)
#pragma unroll
                for (int j = 0; j < 8; ++j)
                    acc[i][j] += av[i] * wv[j];
        }
    }

#pragma unroll
    for (int j = 0; j < 8; ++j) {
        float mm = acc[0][j];
#pragma unroll
        for (int i = 1; i < 8; ++i) mm = fmaxf(mm, acc[i][j]);
        const int o = (j < 4) ? tx * 4 + j : 64 + tx * 4 + (j - 4);
        red[ty * 128 + o] = mm;
    }
    __syncthreads();
    if (threadIdx.x < 128) {
        const int o = threadIdx.x;
        float mm = red[o];
#pragma unroll
        for (int r = 1; r < 16; ++r) mm = fmaxf(mm, red[r * 128 + o]);
        partial[(size_t)pblk * 1024 + ob * 128 + o] = mm + bias[ob * 128 + o];
    }
}

// ----------------------------------------------------------- final reduce
__global__ __launch_bounds__(256) void reduce_kernel(const float* __restrict__ partial,
                                                     float* __restrict__ out) {
    int t = blockIdx.x * 256 + threadIdx.x;   // 16384
    int b = t >> 10, o = t & 1023;
    float m = -INFINITY;
#pragma unroll 4
    for (int i = 0; i < 16; ++i)
        m = fmaxf(m, partial[(size_t)((b * 16 + i) * 1024) + o]);
    out[t] = m;
}

// ---------------------------------------------------------------- launch
extern "C" void kernel_launch(void* const* d_in, const int* in_sizes, int n_in,
                              void* d_out, int out_size, void* d_ws, size_t ws_size,
                              hipStream_t stream) {
    const float* x = (const float*)d_in[0];
    const float* w_edge = (const float*)d_in[1];
    const float* b_edge = (const float*)d_in[2];
    const float* w1 = (const float*)d_in[3];
    const float* b1 = (const float*)d_in[4];
    const float* w2 = (const float*)d_in[5];
    const float* b2 = (const float*)d_in[6];
    const float* w3 = (const float*)d_in[7];
    const float* b3 = (const float*)d_in[8];
    const float* w_final = (const float*)d_in[9];
    const float* b_final = (const float*)d_in[10];
    float* out = (float*)d_out;

    char* ws = (char*)d_ws;
    int* idx = (int*)ws;                                     // 2,621,440 B
    float* cat = (float*)(ws + 2621440);                     // 67,108,864 B
    float* partial = (float*)(ws + 69730304);                // 1,048,576 B
    double* stats = (double*)(ws + 70778880);                // 8,192 B
    __hip_bfloat16* catb = (__hip_bfloat16*)(ws + 70787072); // 33,554,432 B
    __hip_bfloat16* wb = (__hip_bfloat16*)(ws + 104341504);  // 1,048,576 B
    const size_t WS_NEED = 105390080;
    const bool use_mfma = (ws_size >= WS_NEED);
    __hip_bfloat16* catb_arg = use_mfma ? catb : (__hip_bfloat16*)0;

    double* st_e = stats;
    double* st_1 = stats + 128;
    double* st_2 = stats + 256;
    double* st_3 = stats + 512;

    hipMemsetAsync(stats, 0, 1024 * sizeof(double), stream);
    if (use_mfma)
        wconv_kernel<<<2048, 256, 0, stream>>>(w_final, wb);

    knn_kernel<<<B_ * 32, 256, 0, stream>>>(x, idx);
    edge_kernel<<<B_ * 32, 256, 0, stream>>>(x, idx, w_edge, b_edge, cat, st_e);
    bn_kernel<<<(B_ * N_ * 64) / 256, 256, 0, stream>>>(cat, catb_arg, st_e, 64, 0,
                                                        1.0 / ((double)B_ * N_ * KNN));
    layer_kernel<64, 64, 16><<<(B_ * N_) / 64, 256, 0, stream>>>(cat, idx, w1, b1, st_1, 0, 64);
    bn_kernel<<<(B_ * N_ * 64) / 256, 256, 0, stream>>>(cat, catb_arg, st_1, 64, 64,
                                                        1.0 / ((double)B_ * N_));
    layer_kernel<64, 128, 16><<<(B_ * N_) / 32, 256, 0, stream>>>(cat, idx, w2, b2, st_2, 64, 128);
    bn_kernel<<<(B_ * N_ * 128) / 256, 256, 0, stream>>>(cat, catb_arg, st_2, 128, 128,
                                                         1.0 / ((double)B_ * N_));
    layer_kernel<128, 256, 16><<<(B_ * N_) / 16, 256, 0, stream>>>(cat, idx, w3, b3, st_3, 128, 256);
    bn_kernel<<<(B_ * N_ * 256) / 256, 256, 0, stream>>>(cat, catb_arg, st_3, 256, 256,
                                                         1.0 / ((double)B_ * N_));
    if (use_mfma)
        final_mfma_kernel<<<dim3(8, 256), 256, 0, stream>>>((const short*)catb, (const short*)wb,
                                                            b_final, partial);
    else
        final_kernel<<<dim3(8, 256), 256, 0, stream>>>(cat, w_final, b_final, partial);
    reduce_kernel<<<64, 256, 0, stream>>>(partial, out);
}